// Round 3
// baseline (470.266 us; speedup 1.0000x reference)
//
#include <hip/hip_runtime.h>

// ---------- problem constants ----------
#define BATCH 2
#define SEQ   2048
#define HID   2048
#define NH    16
#define NKV   8
#define HD    128
#define M_ROWS (BATCH * SEQ)          // 4096
#define QKV_N  4096                   // 2048 q | 1024 k | 1024 v

typedef __attribute__((ext_vector_type(8))) __bf16 bf16x8;
typedef __attribute__((ext_vector_type(4))) float  f32x4;

static __device__ __forceinline__ f32x4 mfma16(bf16x8 a, bf16x8 b, f32x4 c) {
    return __builtin_amdgcn_mfma_f32_16x16x32_bf16(a, b, c, 0, 0, 0);
}
static __device__ __forceinline__ float sigma_f(float x) {
    return x > 0.f ? x + 1.f : __expf(x);   // elu(x)+1
}
// async global->LDS, 16B per lane; lds base must be wave-uniform
static __device__ __forceinline__ void gload16(const __bf16* g, __bf16* l) {
    __builtin_amdgcn_global_load_lds(
        (const __attribute__((address_space(1))) void*)g,
        (__attribute__((address_space(3))) void*)l, 16, 0, 0);
}

// ---------- workspace layout (bytes) ----------
#define OFF_QKV  0ull                              // float [4096][4096]   64 MB
#define OFF_SQ   67108864ull                       // bf16  (b,h,S,128)    16 MB  (pre-GEMM: hb)
#define OFF_QR   83886080ull                       // bf16  (b,h,S,128)    16 MB  (pre-GEMM: qkvT)
#define OFF_KR   100663296ull                      // bf16  (b,kvh,S,128)   8 MB
#define OFF_VT   109051904ull                      // bf16  (b,kvh,128,S)   8 MB
#define OFF_ND   117440512ull                      // float (b,h,S)       256 KB
#define OFF_CB   117702656ull                      // bf16  [4096][2048]   16 MB
#define OFF_PART 134479872ull                      // float 8*(b,kvh,128,128) 8 MB (late: woT 8 MB)
#define OFF_BND  142868480ull                      // float (b,h,S)       256 KB  (q row-norm^2)
#define OFF_MAXP 143130624ull                      // float (b,kvh,64)     4 KB   (k-norm^2 chunk max)
#define OFF_NPART 143134720ull                     // float 8*(b,kvh,128)  64 KB  (sigma_k col-sum partials)
#define NSPLIT 8

// =====================================================================
// K0a: fp32 -> bf16 bulk convert (8 elems/thread)
// =====================================================================
__global__ void f2b_k(const float* __restrict__ src, __bf16* __restrict__ dst)
{
    const size_t i = ((size_t)blockIdx.x * 256 + threadIdx.x) * 8;
    const float4 v0 = *reinterpret_cast<const float4*>(src + i);
    const float4 v1 = *reinterpret_cast<const float4*>(src + i + 4);
    bf16x8 t;
    t[0]=(__bf16)v0.x; t[1]=(__bf16)v0.y; t[2]=(__bf16)v0.z; t[3]=(__bf16)v0.w;
    t[4]=(__bf16)v1.x; t[5]=(__bf16)v1.y; t[6]=(__bf16)v1.z; t[7]=(__bf16)v1.w;
    *reinterpret_cast<bf16x8*>(dst + i) = t;
}

// =====================================================================
// K0b: W fp32 [K][N] -> Bt bf16 [N][K]  (64x64 LDS tile transpose)
// =====================================================================
__global__ __launch_bounds__(256) void tr_k(const float* __restrict__ W,
                                            __bf16* __restrict__ Bt, int K, int N)
{
    __shared__ __bf16 T[64][72];
    const int k0 = blockIdx.x * 64, n0 = blockIdx.y * 64;
    const int t = threadIdx.x;
    #pragma unroll
    for (int i = 0; i < 4; ++i) {
        const int idx = t + i * 256;           // 0..1023
        const int r = idx >> 4, c4 = (idx & 15) * 4;
        const float4 v = *reinterpret_cast<const float4*>(&W[(size_t)(k0 + r) * N + n0 + c4]);
        T[c4 + 0][r] = (__bf16)v.x; T[c4 + 1][r] = (__bf16)v.y;
        T[c4 + 2][r] = (__bf16)v.z; T[c4 + 3][r] = (__bf16)v.w;
    }
    __syncthreads();
    #pragma unroll
    for (int i = 0; i < 2; ++i) {
        const int idx = t + i * 256;           // 0..511
        const int rr = idx >> 3, cc = (idx & 7) * 8;
        *reinterpret_cast<bf16x8*>(&Bt[(size_t)(n0 + rr) * K + k0 + cc]) =
            *reinterpret_cast<bf16x8*>(&T[rr][cc]);
    }
}

// =====================================================================
// K1 / K8: 256x256-tile 8-phase GEMM (plain-HIP port of the m201 schedule).
// Unchanged from round 2 (verified working, QKV gemm 103 -> off top-5).
// =====================================================================
__global__ __launch_bounds__(512, 2) void gemm8_k(const __bf16* __restrict__ A,
                                                  const __bf16* __restrict__ Bt,
                                                  float* __restrict__ C,
                                                  int N, int K)
{
    __shared__ __align__(16) __bf16 smem[65536];   // 128 KB
    const int tid = threadIdx.x, wave = tid >> 6, lane = tid & 63;
    const int l15 = lane & 15, l4 = lane >> 4;
    const int wr = wave >> 2, wc = wave & 3;

    // bijective XCD swizzle (nwg % 8 == 0 for both call sites)
    const int nwg = gridDim.x;
    const int swz = (blockIdx.x & 7) * (nwg >> 3) + (blockIdx.x >> 3);
    const int NBN = N >> 8;
    const int bm = swz / NBN, bn = swz - bm * NBN;
    const int m0 = bm << 8, n0 = bn << 8;

    const int NKT = K >> 6;

    const int srow   = tid >> 2;                       // 0..127
    const int schunk = (tid & 3) ^ ((tid >> 3) & 3);
    const int sdst   = wave * 512;                     // elems

    const int achunk = l4 ^ ((l15 >> 1) & 3);
    const int aoff = (wr * 128 + l15) * 32 + achunk * 8;
    const int boff = (wc * 64  + l15) * 32 + achunk * 8;

    f32x4 acc[2][4][4] = {};
    bf16x8 af[4], bfr[4];

#define STAGE_SLAB(gb, r0, koff, slabptr) do {                                   \
        const __bf16* _g = (gb) + (size_t)((r0) + srow) * K + (koff) + schunk * 8; \
        gload16(_g,                    (slabptr) + sdst);                        \
        gload16(_g + (size_t)128 * K,  (slabptr) + sdst + 4096);                 \
    } while (0)

    STAGE_SLAB(A,  m0, 0,  smem);              // t0.A0
    STAGE_SLAB(Bt, n0, 0,  smem + 16384);      // t0.B0
    STAGE_SLAB(A,  m0, 32, smem + 8192);       // t0.A1
    STAGE_SLAB(Bt, n0, 32, smem + 24576);      // t0.B1
    STAGE_SLAB(A,  m0, 64, smem + 32768);          // t1.A0
    STAGE_SLAB(Bt, n0, 64, smem + 32768 + 16384);  // t1.B0
    asm volatile("s_waitcnt vmcnt(4)" ::: "memory");
    __builtin_amdgcn_s_barrier();

    #pragma unroll 1
    for (int T = 0; T < NKT; ++T) {
        __bf16* bufc = smem + (T & 1) * 32768;
        __bf16* bufn = smem + ((T & 1) ^ 1) * 32768;
        const int kt1 = (T + 1) * 64, kt2 = (T + 2) * 64;

        // ---- phase 1: khalf 0, mhalf 0 ----
        {
            const __bf16* As = bufc;
            const __bf16* Bs = bufc + 16384;
            #pragma unroll
            for (int f = 0; f < 4; ++f)  af[f]  = *reinterpret_cast<const bf16x8*>(As + aoff + f * 512);
            #pragma unroll
            for (int nf = 0; nf < 4; ++nf) bfr[nf] = *reinterpret_cast<const bf16x8*>(Bs + boff + nf * 512);
            if (T + 1 < NKT) STAGE_SLAB(A, m0, kt1 + 32, bufn + 8192);
            __builtin_amdgcn_s_barrier();
            __builtin_amdgcn_s_setprio(1);
            #pragma unroll
            for (int f = 0; f < 4; ++f)
                #pragma unroll
                for (int nf = 0; nf < 4; ++nf)
                    acc[0][f][nf] = mfma16(af[f], bfr[nf], acc[0][f][nf]);
            __builtin_amdgcn_s_setprio(0);
            __builtin_amdgcn_s_barrier();
        }
        // ---- phase 2: khalf 0, mhalf 1 ----
        {
            const __bf16* As = bufc;
            #pragma unroll
            for (int f = 0; f < 4; ++f)  af[f] = *reinterpret_cast<const bf16x8*>(As + aoff + 2048 + f * 512);
            if (T + 1 < NKT) STAGE_SLAB(Bt, n0, kt1 + 32, bufn + 24576);
            __builtin_amdgcn_s_barrier();
            __builtin_amdgcn_s_setprio(1);
            #pragma unroll
            for (int f = 0; f < 4; ++f)
                #pragma unroll
                for (int nf = 0; nf < 4; ++nf)
                    acc[1][f][nf] = mfma16(af[f], bfr[nf], acc[1][f][nf]);
            __builtin_amdgcn_s_setprio(0);
            __builtin_amdgcn_s_barrier();
        }
        // ---- phase 3: khalf 1, mhalf 0 ----
        {
            const __bf16* As = bufc + 8192;
            const __bf16* Bs = bufc + 24576;
            #pragma unroll
            for (int f = 0; f < 4; ++f)  af[f]  = *reinterpret_cast<const bf16x8*>(As + aoff + f * 512);
            #pragma unroll
            for (int nf = 0; nf < 4; ++nf) bfr[nf] = *reinterpret_cast<const bf16x8*>(Bs + boff + nf * 512);
            if (T + 2 < NKT) STAGE_SLAB(A, m0, kt2, bufc);
            __builtin_amdgcn_s_barrier();
            __builtin_amdgcn_s_setprio(1);
            #pragma unroll
            for (int f = 0; f < 4; ++f)
                #pragma unroll
                for (int nf = 0; nf < 4; ++nf)
                    acc[0][f][nf] = mfma16(af[f], bfr[nf], acc[0][f][nf]);
            __builtin_amdgcn_s_setprio(0);
            __builtin_amdgcn_s_barrier();
        }
        // ---- phase 4: khalf 1, mhalf 1 + boundary vmcnt ----
        {
            const __bf16* As = bufc + 8192;
            #pragma unroll
            for (int f = 0; f < 4; ++f)  af[f] = *reinterpret_cast<const bf16x8*>(As + aoff + 2048 + f * 512);
            if (T + 2 < NKT) STAGE_SLAB(Bt, n0, kt2, bufc + 16384);
            __builtin_amdgcn_s_barrier();
            __builtin_amdgcn_s_setprio(1);
            #pragma unroll
            for (int f = 0; f < 4; ++f)
                #pragma unroll
                for (int nf = 0; nf < 4; ++nf)
                    acc[1][f][nf] = mfma16(af[f], bfr[nf], acc[1][f][nf]);
            __builtin_amdgcn_s_setprio(0);
            if (T < NKT - 2) asm volatile("s_waitcnt vmcnt(4)" ::: "memory");
            else             asm volatile("s_waitcnt vmcnt(0)" ::: "memory");
            __builtin_amdgcn_s_barrier();
        }
    }
#undef STAGE_SLAB

    #pragma unroll
    for (int mh = 0; mh < 2; ++mh)
        #pragma unroll
        for (int f = 0; f < 4; ++f)
            #pragma unroll
            for (int nf = 0; nf < 4; ++nf)
                #pragma unroll
                for (int r = 0; r < 4; ++r) {
                    const int row = m0 + wr * 128 + mh * 64 + f * 16 + l4 * 4 + r;
                    const int col = n0 + wc * 64 + nf * 16 + l15;
                    C[(size_t)row * N + col] = acc[mh][f][nf][r];
                }
}

// =====================================================================
// K2: prep v3 — grid (SEQ/32, NKV, BATCH), 256 threads.
// =====================================================================
__global__ __launch_bounds__(256) void prep_k(const float* __restrict__ qkv,
                                              const float* __restrict__ norm_in,
                                              const int* __restrict__ pos_ids,
                                              __bf16* __restrict__ sq, __bf16* __restrict__ qr,
                                              __bf16* __restrict__ kr, __bf16* __restrict__ vt,
                                              float* __restrict__ nd, float* __restrict__ bnd,
                                              float* __restrict__ maxp)
{
    const int sc = blockIdx.x, kvh = blockIdx.y, b = blockIdx.z;
    const int s0 = sc * 32, t = threadIdx.x;
    const float scale = 0.08838834764831845f;      // 1/sqrt(128)
    const float s2 = scale * scale;
    const float NEG_LN_TH = -0.14391156831212787f; // -ln(10000)/64
    __shared__ float krn[32];

    // ---------- Q phase: 64 rows (2 heads x 32 s), 4 threads/row ----------
    {
        const int row = t >> 2;             // 0..63
        const int head = row >> 5, sl = row & 31;
        const int hq = kvh * 2 + head, nh = hq & 7;
        const int dq = (t & 3) * 16;        // pair-halves [dq,dq+16) & [dq+64,dq+80)
        const int pos = pos_ids[s0 + sl];
        const float* qp = qkv + (size_t)(b * SEQ + s0 + sl) * QKV_N + hq * 128;
        const float* np = norm_in + (b * NKV + nh) * 128;

        float x0[16], x1[16];
        #pragma unroll
        for (int i = 0; i < 16; i += 4) {
            *reinterpret_cast<float4*>(&x0[i]) = *reinterpret_cast<const float4*>(qp + dq + i);
            *reinterpret_cast<float4*>(&x1[i]) = *reinterpret_cast<const float4*>(qp + dq + 64 + i);
        }
        float nds = 0.f, qns = 0.f;
        bf16x8 sqv0[2], sqv1[2], qrv0[2], qrv1[2];
        #pragma unroll
        for (int i = 0; i < 16; ++i) {
            const int j = dq + i;           // 0..63
            float c, sn;
            __sincosf((float)pos * __expf((float)j * NEG_LN_TH), &sn, &c);
            qrv0[i >> 3][i & 7] = (__bf16)((x0[i] * c - x1[i] * sn) * scale);
            qrv1[i >> 3][i & 7] = (__bf16)((x1[i] * c + x0[i] * sn) * scale);
            const float sg0 = sigma_f(x0[i]), sg1 = sigma_f(x1[i]);
            sqv0[i >> 3][i & 7] = (__bf16)sg0;
            sqv1[i >> 3][i & 7] = (__bf16)sg1;
            nds += sg0 * np[j] + sg1 * np[j + 64];
            qns += (x0[i] * x0[i] + x1[i] * x1[i]) * s2;
        }
        __bf16* sqp = sq + ((size_t)(b * NH + hq) * SEQ + s0 + sl) * 128;
        __bf16* qrp = qr + ((size_t)(b * NH + hq) * SEQ + s0 + sl) * 128;
        *reinterpret_cast<bf16x8*>(sqp + dq)      = sqv0[0];
        *reinterpret_cast<bf16x8*>(sqp + dq + 8)  = sqv0[1];
        *reinterpret_cast<bf16x8*>(sqp + dq + 64) = sqv1[0];
        *reinterpret_cast<bf16x8*>(sqp + dq + 72) = sqv1[1];
        *reinterpret_cast<bf16x8*>(qrp + dq)      = qrv0[0];
        *reinterpret_cast<bf16x8*>(qrp + dq + 8)  = qrv0[1];
        *reinterpret_cast<bf16x8*>(qrp + dq + 64) = qrv1[0];
        *reinterpret_cast<bf16x8*>(qrp + dq + 72) = qrv1[1];

        nds += __shfl_xor(nds, 1); nds += __shfl_xor(nds, 2);
        qns += __shfl_xor(qns, 1); qns += __shfl_xor(qns, 2);
        if ((t & 3) == 0) {
            nd [(size_t)(b * NH + hq) * SEQ + s0 + sl] = nds;
            bnd[(size_t)(b * NH + hq) * SEQ + s0 + sl] = qns;
        }
    }

    // ---------- K phase: 32 rows, 4 threads/row (threads 0..127) ----------
    if (t < 128) {
        const int sl = t >> 2;
        const int dq = (t & 3) * 16;
        const int pos = pos_ids[s0 + sl];
        const float* kp = qkv + (size_t)(b * SEQ + s0 + sl) * QKV_N + 2048 + kvh * 128;
        float x0[16], x1[16];
        #pragma unroll
        for (int i = 0; i < 16; i += 4) {
            *reinterpret_cast<float4*>(&x0[i]) = *reinterpret_cast<const float4*>(kp + dq + i);
            *reinterpret_cast<float4*>(&x1[i]) = *reinterpret_cast<const float4*>(kp + dq + 64 + i);
        }
        bf16x8 kv0[2], kv1[2];
        float kns = 0.f;
        #pragma unroll
        for (int i = 0; i < 16; ++i) {
            const int j = dq + i;
            float c, sn;
            __sincosf((float)pos * __expf((float)j * NEG_LN_TH), &sn, &c);
            kv0[i >> 3][i & 7] = (__bf16)(x0[i] * c - x1[i] * sn);
            kv1[i >> 3][i & 7] = (__bf16)(x1[i] * c + x0[i] * sn);
            kns += x0[i] * x0[i] + x1[i] * x1[i];
        }
        __bf16* krp = kr + ((size_t)(b * NKV + kvh) * SEQ + s0 + sl) * 128;
        *reinterpret_cast<bf16x8*>(krp + dq)      = kv0[0];
        *reinterpret_cast<bf16x8*>(krp + dq + 8)  = kv0[1];
        *reinterpret_cast<bf16x8*>(krp + dq + 64) = kv1[0];
        *reinterpret_cast<bf16x8*>(krp + dq + 72) = kv1[1];
        kns += __shfl_xor(kns, 1); kns += __shfl_xor(kns, 2);
        if ((t & 3) == 0) krn[sl] = kns;
    }

    // ---------- V phase: transpose via LDS, coalesced vt writes ----------
    __shared__ float vl[128][33];
    {
        const int sl = t >> 3, dch = (t & 7) * 16;
        const float* vp = qkv + (size_t)(b * SEQ + s0 + sl) * QKV_N + 3072 + kvh * 128 + dch;
        float xv[16];
        #pragma unroll
        for (int i = 0; i < 16; i += 4)
            *reinterpret_cast<float4*>(&xv[i]) = *reinterpret_cast<const float4*>(vp + i);
        #pragma unroll
        for (int i = 0; i < 16; ++i) vl[dch + i][sl] = xv[i];
    }
    __syncthreads();
    if (t == 0) {
        float mx = 0.f;
        #pragma unroll
        for (int i = 0; i < 32; ++i) mx = fmaxf(mx, krn[i]);
        maxp[((b * NKV + kvh) << 6) + sc] = mx;
    }
    {
        const int d = t >> 1, sh = (t & 1) * 16;
        bf16x8 o0, o1;
        #pragma unroll
        for (int j = 0; j < 8; ++j) o0[j] = (__bf16)vl[d][sh + j];
        #pragma unroll
        for (int j = 0; j < 8; ++j) o1[j] = (__bf16)vl[d][sh + 8 + j];
        __bf16* vp = vt + ((size_t)((b * NKV + kvh) * 128 + d)) * SEQ + s0 + sh;
        *reinterpret_cast<bf16x8*>(vp)     = o0;
        *reinterpret_cast<bf16x8*>(vp + 8) = o1;
    }
}

// =====================================================================
// K3: memory_output = (sigma_q @ mem) / nd, write g*val into combined
// =====================================================================
__global__ __launch_bounds__(256) void memout_k(const __bf16* __restrict__ sq,
                                                const float* __restrict__ mem_in,
                                                const float* __restrict__ nd,
                                                const float* __restrict__ gate,
                                                __bf16* __restrict__ cb)
{
    __shared__ __align__(16) __bf16 mt[128][136];   // mem^T [e][d]
    const int tid = threadIdx.x;
    const int h = blockIdx.y, b = blockIdx.z;
    const int s0 = blockIdx.x * 64;

    const float* mem = mem_in + (size_t)(b * NKV + (h & 7)) * 16384;
    for (int i = tid; i < 16384; i += 256) {
        int dd = i >> 7, e = i & 127;
        mt[e][dd] = (__bf16)mem[i];
    }
    __syncthreads();

    const int wave = tid >> 6, lane = tid & 63, l15 = lane & 15, l4 = lane >> 4;
    f32x4 acc[8] = {};
    const __bf16* sqb = sq + ((size_t)(b * NH + h) * SEQ + s0 + wave * 16 + l15) * 128;
    #pragma unroll
    for (int kb = 0; kb < 4; ++kb) {
        bf16x8 a = *reinterpret_cast<const bf16x8*>(sqb + kb * 32 + l4 * 8);
        #pragma unroll
        for (int nc = 0; nc < 8; ++nc) {
            bf16x8 bb = *reinterpret_cast<bf16x8*>(&mt[nc * 16 + l15][kb * 32 + l4 * 8]);
            acc[nc] = mfma16(a, bb, acc[nc]);
        }
    }
    float g = 1.f / (1.f + __expf(-gate[h]));
    #pragma unroll
    for (int r = 0; r < 4; ++r) {
        int srow = s0 + wave * 16 + l4 * 4 + r;
        float scl = g / nd[(size_t)(b * NH + h) * SEQ + srow];
        __bf16* cbp = cb + (size_t)(b * SEQ + srow) * HID + h * 128;
        #pragma unroll
        for (int nc = 0; nc < 8; ++nc)
            cbp[nc * 16 + l15] = (__bf16)(acc[nc][r] * scl);
    }
}

// =====================================================================
// K5: updated_memory partials + sigma_k column-sum partials.
// =====================================================================
__global__ __launch_bounds__(256) void memupd_k(const float* __restrict__ qkv,
                                                float* __restrict__ part,
                                                float* __restrict__ npart)
{
    const int sp = blockIdx.x, h = blockIdx.y, b = blockIdx.z;
    const int tid = threadIdx.x;
    const int tx = tid & 15, ty = tid >> 4;   // d-block tx*8, e-block ty*8
    __shared__ __align__(16) float sk[8][128];
    __shared__ __align__(16) float sv[8][128];
    float acc[8][8] = {};
    float nacc = 0.f;                          // threads 0..127: sum_s sigma_k[.,tid]

    const int s0 = sp * (SEQ / NSPLIT);
    for (int so = 0; so < SEQ / NSPLIT; so += 8) {
        for (int i = tid; i < 8 * 128; i += 256) {
            int rr = i >> 7, dd = i & 127;
            const float* rowp = qkv + (size_t)(b * SEQ + s0 + so + rr) * QKV_N;
            sk[rr][dd] = sigma_f(rowp[2048 + h * 128 + dd]);
            sv[rr][dd] = rowp[3072 + h * 128 + dd];
        }
        __syncthreads();
        if (tid < 128) {
            #pragma unroll
            for (int rr = 0; rr < 8; ++rr) nacc += sk[rr][tid];
        }
        #pragma unroll
        for (int rr = 0; rr < 8; ++rr) {
            float4 k0 = *reinterpret_cast<float4*>(&sk[rr][tx * 8]);
            float4 k1 = *reinterpret_cast<float4*>(&sk[rr][tx * 8 + 4]);
            float4 v0 = *reinterpret_cast<float4*>(&sv[rr][ty * 8]);
            float4 v1 = *reinterpret_cast<float4*>(&sv[rr][ty * 8 + 4]);
            float kreg[8] = {k0.x,k0.y,k0.z,k0.w,k1.x,k1.y,k1.z,k1.w};
            float vreg[8] = {v0.x,v0.y,v0.z,v0.w,v1.x,v1.y,v1.z,v1.w};
            #pragma unroll
            for (int i = 0; i < 8; ++i)
                #pragma unroll
                for (int j2 = 0; j2 < 8; ++j2)
                    acc[i][j2] += kreg[i] * vreg[j2];
        }
        __syncthreads();
    }
    float* pb = part + ((size_t)sp * (BATCH * NKV) + b * NKV + h) * 16384;
    #pragma unroll
    for (int i = 0; i < 8; ++i)
        #pragma unroll
        for (int j2 = 0; j2 < 8; ++j2)
            pb[(tx * 8 + i) * 128 + ty * 8 + j2] = acc[i][j2];
    if (tid < 128)
        npart[((size_t)sp * (BATCH * NKV) + b * NKV + h) * 128 + tid] = nacc;
}

// K6: reduce partials + memory_in
__global__ void memred_k(const float* __restrict__ part, const float* __restrict__ mem_in,
                         float* __restrict__ out_mem)
{
    const size_t i = (size_t)blockIdx.x * 256 + threadIdx.x;   // 262144 total
    float a = mem_in[i];
    #pragma unroll
    for (int sp = 0; sp < NSPLIT; ++sp) a += part[(size_t)sp * 262144 + i];
    out_mem[i] = a;
}

// K6b: updated_norm = norm_in + sum_sp npart
__global__ void normred_k(const float* __restrict__ npart, const float* __restrict__ norm_in,
                          float* __restrict__ out_norm)
{
    const int bh = blockIdx.x, d = threadIdx.x;    // 16 blocks x 128 threads
    float a = norm_in[bh * 128 + d];
    #pragma unroll
    for (int sp = 0; sp < NSPLIT; ++sp)
        a += npart[((size_t)sp * (BATCH * NKV) + bh) * 128 + d];
    out_norm[bh * 128 + d] = a;
}

// =====================================================================
// K7: flash causal attention v5.
// Same math/layout as v4 (kt-parity wave split, swizzled K/V LDS), new:
//  - split-phase staging: K(t+1) issued after QK-barrier, V(t+1) after
//    PV-barrier; counted s_waitcnt vmcnt(8) (never 0 in steady state);
//    exp/P phase slotted between issue and wait to hide latency.
//  - all LDS accesses as precomputed per-lane base + compile-time
//    immediate (swizzle XOR split into disjoint bit-fields).
//  - plds de-swizzled (1 write base + 1 read base + immediates).
//  - setprio(1) around QK and PV MFMA clusters.
// LDS unchanged: 80 KB -> 2 blocks/CU.
// =====================================================================
__global__ __launch_bounds__(256, 2) void attn_k(const __bf16* __restrict__ qr,
                                                 const __bf16* __restrict__ kr,
                                                 const __bf16* __restrict__ vt,
                                                 const float* __restrict__ gate,
                                                 const float* __restrict__ bnd,
                                                 const float* __restrict__ maxp,
                                                 __bf16* __restrict__ cb)
{
    __shared__ __align__(16) char smem[81920];
    char* ksB = smem;                        // K swz [128][128] bf16 (32 KB)
    char* vsB = smem + 32768;                // V^T swz [128][128]    (32 KB)
    char* pB  = smem + 65536;                // plds 4 x [32][64] lin (16 KB)
    float*  red  = (float*)smem;             // epilogue overlay
    float*  lred = (float*)(smem + 65536);   // epilogue overlay

    const int tid = threadIdx.x, wave = tid >> 6, lane = tid & 63;
    const int l15 = lane & 15, l4 = lane >> 4;
    const int e3 = l15 & 7, e2 = e3 >> 2;
    const int ksub = wave >> 1;                        // k-subtile parity
    const int wq   = wave & 1;                         // q 32-row half

    // ---- XCD swizzle: each XCD owns 2 full (b,kvh) groups ----
    const int n   = blockIdx.x + 16 * (blockIdx.y + 16 * blockIdx.z);
    const int xcd = n & 7, i64 = n >> 3;
    const int grp = xcd * 2 + (i64 >> 5);
    const int within = i64 & 31;
    const int b   = grp >> 3;
    const int kvh = grp & 7;
    const int h   = kvh * 2 + (within >> 4);
    const int x   = within & 15;

    const __bf16* kbase = kr + (size_t)(b * NKV + kvh) * SEQ * 128;
    const __bf16* vbase = vt + (size_t)(b * NKV + kvh) * 128 * SEQ;
    const float* bbase  = bnd + (size_t)(b * NH + h) * SEQ;

    const float g  = 1.f / (1.f + __expf(-gate[h]));
    const float gi = 1.f - g;
    float kn2 = 0.f;
    const float* mp = maxp + (b * NKV + kvh) * 64;
    #pragma unroll
    for (int i = 0; i < 64; i += 4) {
        const float4 v = *reinterpret_cast<const float4*>(mp + i);
        kn2 = fmaxf(kn2, fmaxf(fmaxf(v.x, v.y), fmaxf(v.z, v.w)));
    }
    const float knmax = sqrtf(kn2);

    bf16x8 ones;
    #pragma unroll
    for (int j = 0; j < 8; ++j) ones[j] = (__bf16)1.0f;

    // ---- precomputed staging addresses (bytes) ----
    // LDS row r chunk c holds global chunk c ^ (r&7); source pre-swizzled.
    const int srow = wave * 32 + l4;                   // + j*4 per issue
    const int chA  = (lane & 15) ^ l4;
    const char* KG0 = (const char*)kbase + srow * 256 + chA * 16;          // j even
    const char* KG1 = (const char*)kbase + srow * 256 + ((chA ^ 4) * 16);  // j odd
    const char* VG0 = (const char*)vbase + srow * 4096 + chA * 16;
    const char* VG1 = (const char*)vbase + srow * 4096 + ((chA ^ 4) * 16);
    __bf16* kdst = (__bf16*)(ksB + wave * 8192);
    __bf16* vdst = (__bf16*)(vsB + wave * 8192);

    // ---- precomputed read bases (byte offsets; XOR split into fields) ----
    // K: addr(sub,kb) = KB[kb&1] + sub*4096 + (kb>>1)*128
    const int t16 = (l4 ^ (e3 & 3)) * 16;
    const int KBe = l15 * 256 + ksub * 16384 + t16 + e2 * 64;
    const int KBo = l15 * 256 + ksub * 16384 + t16 + (1 ^ e2) * 64;
    // V: addr(nc,half) = VB[half] + nc*4096
    const int VB0 = l15 * 256 + t16 + e2 * 64 + ksub * 128;
    const int VB1 = l15 * 256 + t16 + (1 ^ e2) * 64 + ksub * 128;
    // plds (linear): write base + {r*128 + sub*32 + m*2048}; read base + {m*2048 + half*64}
    const int PWw = wave * 4096 + l4 * 512 + l15 * 2;
    const int PWr = wave * 4096 + l15 * 128 + l4 * 16;

#define ISSUE_K(ktrow) do {                                                      \
        const int _ko = (ktrow) * 256;                                           \
        _Pragma("unroll")                                                        \
        for (int _j = 0; _j < 8; ++_j)                                           \
            gload16((const __bf16*)(((_j & 1) ? KG1 : KG0) + _ko + _j * 1024),   \
                    kdst + _j * 512);                                            \
    } while (0)
#define ISSUE_V(ktrow) do {                                                      \
        const int _vo = (ktrow) * 2;                                             \
        _Pragma("unroll")                                                        \
        for (int _j = 0; _j < 8; ++_j)                                           \
            gload16((const __bf16*)(((_j & 1) ? VG1 : VG0) + _vo + _j * 16384),  \
                    vdst + _j * 512);                                            \
    } while (0)

    #pragma unroll 1
    for (int tile = 0; tile < 2; ++tile) {
        const int q0 = (tile == 0 ? x : 31 - x) * 64;
        const int qw = q0 + wq * 32;
        const int NT = (q0 >> 6) + 1;                  // # 64-kt subtiles
        const int NI = (NT + 1) >> 1;                  // 128-kt iterations

        bf16x8 af[2][4];
        float m_r[2][4];
        #pragma unroll
        for (int m = 0; m < 2; ++m) {
            const __bf16* qb = qr + ((size_t)(b * NH + h) * SEQ + qw + m * 16 + l15) * 128;
            #pragma unroll
            for (int kb = 0; kb < 4; ++kb)
                af[m][kb] = *reinterpret_cast<const bf16x8*>(qb + kb * 32 + l4 * 8);
            #pragma unroll
            for (int r = 0; r < 4; ++r)
                m_r[m][r] = sqrtf(bbase[qw + m * 16 + l4 * 4 + r]) * knmax + 1.0f;
        }

        f32x4 o0[8] = {}, o1[8] = {};
        f32x4 lc0 = {}, lc1 = {};

        // ---- prologue: stage iter-0 K and V ----
        ISSUE_K(0);
        ISSUE_V(0);
        asm volatile("s_waitcnt vmcnt(8)" ::: "memory");   // K(0) landed
        __builtin_amdgcn_sched_barrier(0);
        __builtin_amdgcn_s_barrier();

        #pragma unroll 1
        for (int it = 0; it < NI; ++it) {
            const int s = 2 * it + ksub;
            const bool act  = (s < NT);
            const bool more = (it + 1 < NI);

            f32x4 s0[4] = {}, s1[4] = {};
            if (act) {
                // ---- QK^T (Ks reads: 2 bases + immediates) ----
                __builtin_amdgcn_s_setprio(1);
                #pragma unroll
                for (int kb = 0; kb < 4; ++kb) {
                    const int kbb = ((kb & 1) ? KBo : KBe) + (kb >> 1) * 128;
                    #pragma unroll
                    for (int sub = 0; sub < 4; ++sub) {
                        bf16x8 bb = *reinterpret_cast<const bf16x8*>(ksB + kbb + sub * 4096);
                        s0[sub] = mfma16(af[0][kb], bb, s0[sub]);
                        s1[sub] = mfma16(af[1][kb], bb, s1[sub]);
                    }
                }
                __builtin_amdgcn_s_setprio(0);
            }
            __builtin_amdgcn_sched_barrier(0);
            __builtin_amdgcn_s_barrier();              // (1) all done reading Ks(it)

            if (more) ISSUE_K((it + 1) * 128);

            if (act) {
                // ---- exp + causal mask + plds store (wave-local) ----
                #pragma unroll
                for (int r = 0; r < 4; ++r) {
                    const int q0r = qw + l4 * 4 + r;
                    const int q1r = q0r + 16;
                    #pragma unroll
                    for (int sub = 0; sub < 4; ++sub) {
                        const int key = s * 64 + sub * 16 + l15;
                        float p0 = __expf(s0[sub][r] - m_r[0][r]);
                        float p1 = __expf(s1[sub][r] - m_r[1][r]);
                        p0 = (key <= q0r) ? p0 : 0.f;
                        p1 = (key <= q1r) ? p1 : 0.f;
                        *(__bf16*)(pB + PWw + r * 128 + sub * 32)        = (__bf16)p0;
                        *(__bf16*)(pB + PWw + 2048 + r * 128 + sub * 32) = (__bf16)p1;
                    }
                }
            }
            if (more) asm volatile("s_waitcnt vmcnt(8)" ::: "memory");  // V(it) landed
            else      asm volatile("s_waitcnt vmcnt(0)" ::: "memory");
            __builtin_amdgcn_sched_barrier(0);
            __builtin_amdgcn_s_barrier();              // (2) Vs(it) visible

            if (act) {
                // ---- P reads (1 base + immediates) + PV ----
                bf16x8 a00 = *reinterpret_cast<const bf16x8*>(pB + PWr);
                bf16x8 a01 = *reinterpret_cast<const bf16x8*>(pB + PWr + 64);
                bf16x8 a10 = *reinterpret_cast<const bf16x8*>(pB + PWr + 2048);
                bf16x8 a11 = *reinterpret_cast<const bf16x8*>(pB + PWr + 2048 + 64);
                __builtin_amdgcn_s_setprio(1);
                lc0 = mfma16(a00, ones, lc0); lc0 = mfma16(a01, ones, lc0);
                lc1 = mfma16(a10, ones, lc1); lc1 = mfma16(a11, ones, lc1);
                #pragma unroll
                for (int nc = 0; nc < 8; ++nc) {
                    bf16x8 b0 = *reinterpret_cast<const bf16x8*>(vsB + VB0 + nc * 4096);
                    bf16x8 b1 = *reinterpret_cast<const bf16x8*>(vsB + VB1 + nc * 4096);
                    o0[nc] = mfma16(a00, b0, o0[nc]); o0[nc] = mfma16(a01, b1, o0[nc]);
                    o1[nc] = mfma16(a10, b0, o1[nc]); o1[nc] = mfma16(a11, b1, o1[nc]);
                }
                __builtin_amdgcn_s_setprio(0);
            }
            __builtin_amdgcn_sched_barrier(0);
            __builtin_amdgcn_s_barrier();              // (3) all done reading Vs(it)

            if (more) {
                ISSUE_V((it + 1) * 128);
                asm volatile("s_waitcnt vmcnt(8)" ::: "memory");        // K(it+1) landed
            } else {
                asm volatile("s_waitcnt vmcnt(0)" ::: "memory");
            }
            __builtin_amdgcn_sched_barrier(0);
            __builtin_amdgcn_s_barrier();              // (4) Ks(it+1) visible
        }

        // ---- cross-pair reduction: wave w+2 -> wave w (same q-rows) ----
        if (wave >= 2) {
            float* rb = red + (wave - 2) * 4224;       // 32 rows x stride 132
            #pragma unroll
            for (int nc = 0; nc < 8; ++nc)
                #pragma unroll
                for (int r = 0; r < 4; ++r) {
                    rb[(l4 * 4 + r) * 132 + nc * 16 + l15]        = o0[nc][r];
                    rb[(16 + l4 * 4 + r) * 132 + nc * 16 + l15]   = o1[nc][r];
                }
            if (l15 == 0) {
                float* lb = lred + (wave - 2) * 32;
                #pragma unroll
                for (int r = 0; r < 4; ++r) {
                    lb[l4 * 4 + r]      = lc0[r];
                    lb[16 + l4 * 4 + r] = lc1[r];
                }
            }
        }
        __syncthreads();
        if (wave < 2) {
            float* rb = red + wave * 4224;
            const float* lb = lred + wave * 32;
            #pragma unroll
            for (int r = 0; r < 4; ++r) {
                const int qrow = qw + l4 * 4 + r;
                const float i0 = gi / (lc0[r] + lb[l4 * 4 + r]);
                const float i1 = gi / (lc1[r] + lb[16 + l4 * 4 + r]);
                __bf16* c0 = cb + (size_t)(b * SEQ + qrow) * HID + h * 128;
                __bf16* c1 = cb + (size_t)(b * SEQ + qrow + 16) * HID + h * 128;
                #pragma unroll
                for (int nc = 0; nc < 8; ++nc) {
                    const int dd = nc * 16 + l15;
                    const float v0 = o0[nc][r] + rb[(l4 * 4 + r) * 132 + dd];
                    const float v1 = o1[nc][r] + rb[(16 + l4 * 4 + r) * 132 + dd];
                    c0[dd] = (__bf16)((float)c0[dd] + v0 * i0);
                    c1[dd] = (__bf16)((float)c1[dd] + v1 * i1);
                }
            }
        }
        __syncthreads();   // red/lred overlay dead before next tile restages Ks
    }
#undef ISSUE_K
#undef ISSUE_V
}

// =====================================================================
extern "C" void kernel_launch(void* const* d_in, const int* in_sizes, int n_in,
                              void* d_out, int out_size, void* d_ws, size_t ws_size,
                              hipStream_t stream)
{
    const float* hidden  = (const float*)d_in[0];
    const float* Wq      = (const float*)d_in[1];
    const float* Wk      = (const float*)d_in[2];
    const float* Wv      = (const float*)d_in[3];
    const float* Wo      = (const float*)d_in[4];
    const float* gate    = (const float*)d_in[5];
    const float* mem_in  = (const float*)d_in[6];
    const float* norm_in = (const float*)d_in[7];
    const int*   pos     = (const int*)d_in[8];

    float* out_final = (float*)d_out;                  // (B,S,HID)
    float* out_mem   = out_final + (size_t)BATCH * SEQ * HID;     // (B,8,128,128)
    float* out_norm  = out_mem + (size_t)BATCH * NKV * 128 * 128; // (B,8,1,128)

    char* ws = (char*)d_ws;
    float*  qkv  = (float*)(ws + OFF_QKV);
    __bf16* sq   = (__bf16*)(ws + OFF_SQ);
    __bf16* qrb  = (__bf16*)(ws + OFF_QR);
    __bf16* krb  = (__bf16*)(ws + OFF_KR);
    __bf16* vtb  = (__bf16*)(ws + OFF_VT);
    float*  nd   = (float*)(ws + OFF_ND);
    __bf16* cb   = (__bf16*)(ws + OFF_CB);
    float*  part = (float*)(ws + OFF_PART);
    float*  bnd  = (float*)(ws + OFF_BND);
    float*  maxp = (float*)(ws + OFF_MAXP);
    float*  npart = (float*)(ws + OFF_NPART);
    // overlays (lifetimes disjoint from the named owners):
    __bf16* hb   = (__bf16*)(ws + OFF_SQ);    // bf16 hidden  [4096][2048], dead after gemm1
    __bf16* qkvT = (__bf16*)(ws + OFF_QR);    // bf16 W_qkv^T [4096][2048], dead after gemm1
    __bf16* woT  = (__bf16*)(ws + OFF_PART);  // bf16 Wo^T    [2048][2048], after memred

    // 0. bf16 conversions / weight transposes
    f2b_k<<<(M_ROWS * HID) / (256 * 8), 256, 0, stream>>>(hidden, hb);
    tr_k<<<dim3(HID / 64, 2048 / 64), 256, 0, stream>>>(Wq, qkvT, HID, 2048);
    tr_k<<<dim3(HID / 64, 1024 / 64), 256, 0, stream>>>(Wk, qkvT + (size_t)2048 * HID, HID, 1024);
    tr_k<<<dim3(HID / 64, 1024 / 64), 256, 0, stream>>>(Wv, qkvT + (size_t)3072 * HID, HID, 1024);

    // 1. fused QKV projection: [4096 x 2048] @ [2048 x 4096], 256 blocks (1/CU)
    gemm8_k<<<(M_ROWS / 256) * (QKV_N / 256), 512, 0, stream>>>(hb, qkvT, qkv, QKV_N, HID);

    // 2. prep (overwrites hb/qkvT — now dead); k-norm maxima fused in
    prep_k<<<dim3(SEQ / 32, NKV, BATCH), 256, 0, stream>>>(qkv, norm_in, pos, sq, qrb, krb, vtb,
                                                           nd, bnd, maxp);

    // 3. memory_output -> combined (g * memout / nd)
    memout_k<<<dim3(SEQ / 64, NH, BATCH), 256, 0, stream>>>(sq, mem_in, nd, gate, cb);

    // 4/5. updated_memory (+ sigma_k col-sum partials)
    memupd_k<<<dim3(NSPLIT, NKV, BATCH), 256, 0, stream>>>(qkv, part, npart);
    memred_k<<<(BATCH * NKV * 128 * 128) / 256, 256, 0, stream>>>(part, mem_in, out_mem);
    normred_k<<<BATCH * NKV, 128, 0, stream>>>(npart, norm_in, out_norm);

    // 6b. Wo^T (overlays part — dead after memred)
    tr_k<<<dim3(HID / 64, HID / 64), 256, 0, stream>>>(Wo, woT, HID, HID);

    // 7. causal attention v5 (split-phase staging, counted vmcnt, base+imm LDS)
    attn_k<<<dim3(16, NH, BATCH), 256, 0, stream>>>(qrb, krb, vtb, gate, bnd, maxp, cb);

    // 8. output projection: [4096 x 2048] @ [2048 x 2048], 128 blocks
    gemm8_k<<<(M_ROWS / 256) * (HID / 256), 512, 0, stream>>>(cb, woT, out_final, HID, HID);
}

// Round 4
// 440.084 us; speedup vs baseline: 1.0686x; 1.0686x over previous
//
#include <hip/hip_runtime.h>

// ---------- problem constants ----------
#define BATCH 2
#define SEQ   2048
#define HID   2048
#define NH    16
#define NKV   8
#define HD    128
#define M_ROWS (BATCH * SEQ)          // 4096
#define QKV_N  4096                   // 2048 q | 1024 k | 1024 v

typedef __attribute__((ext_vector_type(8))) __bf16 bf16x8;
typedef __attribute__((ext_vector_type(4))) float  f32x4;

static __device__ __forceinline__ f32x4 mfma16(bf16x8 a, bf16x8 b, f32x4 c) {
    return __builtin_amdgcn_mfma_f32_16x16x32_bf16(a, b, c, 0, 0, 0);
}
static __device__ __forceinline__ float sigma_f(float x) {
    return x > 0.f ? x + 1.f : __expf(x);   // elu(x)+1
}
// async global->LDS, 16B per lane; lds base must be wave-uniform
static __device__ __forceinline__ void gload16(const __bf16* g, __bf16* l) {
    __builtin_amdgcn_global_load_lds(
        (const __attribute__((address_space(1))) void*)g,
        (__attribute__((address_space(3))) void*)l, 16, 0, 0);
}

// ---------- workspace layout (bytes) ----------
#define OFF_QKV  0ull                              // float [4096][4096]   64 MB
#define OFF_SQ   67108864ull                       // bf16  (b,h,S,128)    16 MB  (pre-GEMM: hb)
#define OFF_QR   83886080ull                       // bf16  (b,h,S,128)    16 MB  (pre-GEMM: qkvT)
#define OFF_KR   100663296ull                      // bf16  (b,kvh,S,128)   8 MB
#define OFF_VT   109051904ull                      // bf16  (b,kvh,128,S)   8 MB
#define OFF_ND   117440512ull                      // float (b,h,S)       256 KB
#define OFF_CB   117702656ull                      // bf16  [4096][2048]   16 MB
#define OFF_PART 134479872ull                      // float 8*(b,kvh,128,128) 8 MB (late: woT 8 MB)
#define OFF_BND  142868480ull                      // float (b,h,S)       256 KB  (q row-norm^2)
#define OFF_MAXP 143130624ull                      // float (b,kvh,64)     4 KB   (k-norm^2 chunk max)
#define OFF_NPART 143134720ull                     // float 8*(b,kvh,128)  64 KB  (sigma_k col-sum partials)
#define NSPLIT 8

// =====================================================================
// K0: fused pre-pass — f2b (hidden fp32->bf16) + Wq/Wk/Wv transposes.
// grid: [0,4096) f2b ; [4096,5120) Wq ; [5120,5632) Wk ; [5632,6144) Wv
// =====================================================================
__global__ __launch_bounds__(256) void pre_k(const float* __restrict__ hidden,
                                             const float* __restrict__ Wq,
                                             const float* __restrict__ Wk,
                                             const float* __restrict__ Wv,
                                             __bf16* __restrict__ hb,
                                             __bf16* __restrict__ qkvT)
{
    __shared__ __bf16 T[64][72];
    const int bid = blockIdx.x;
    const int t = threadIdx.x;
    if (bid < 4096) {
        const size_t i = ((size_t)bid * 256 + t) * 8;
        const float4 v0 = *reinterpret_cast<const float4*>(hidden + i);
        const float4 v1 = *reinterpret_cast<const float4*>(hidden + i + 4);
        bf16x8 o;
        o[0]=(__bf16)v0.x; o[1]=(__bf16)v0.y; o[2]=(__bf16)v0.z; o[3]=(__bf16)v0.w;
        o[4]=(__bf16)v1.x; o[5]=(__bf16)v1.y; o[6]=(__bf16)v1.z; o[7]=(__bf16)v1.w;
        *reinterpret_cast<bf16x8*>(hb + i) = o;
        return;
    }
    int tb = bid - 4096;
    const float* W; __bf16* Bt; int N;
    if (tb < 1024)      { W = Wq; Bt = qkvT;                         N = 2048; }
    else if (tb < 1536) { W = Wk; Bt = qkvT + (size_t)2048 * HID;    N = 1024; tb -= 1024; }
    else                { W = Wv; Bt = qkvT + (size_t)3072 * HID;    N = 1024; tb -= 1536; }
    const int k0 = (tb & 31) * 64, n0 = (tb >> 5) * 64;
    #pragma unroll
    for (int i = 0; i < 4; ++i) {
        const int idx = t + i * 256;
        const int r = idx >> 4, c4 = (idx & 15) * 4;
        const float4 v = *reinterpret_cast<const float4*>(&W[(size_t)(k0 + r) * N + n0 + c4]);
        T[c4 + 0][r] = (__bf16)v.x; T[c4 + 1][r] = (__bf16)v.y;
        T[c4 + 2][r] = (__bf16)v.z; T[c4 + 3][r] = (__bf16)v.w;
    }
    __syncthreads();
    #pragma unroll
    for (int i = 0; i < 2; ++i) {
        const int idx = t + i * 256;
        const int rr = idx >> 3, cc = (idx & 7) * 8;
        *reinterpret_cast<bf16x8*>(&Bt[(size_t)(n0 + rr) * HID + k0 + cc]) =
            *reinterpret_cast<bf16x8*>(&T[rr][cc]);
    }
}

// =====================================================================
// K0b: W fp32 [K][N] -> Bt bf16 [N][K]  (64x64 LDS tile transpose) — Wo only
// =====================================================================
__global__ __launch_bounds__(256) void tr_k(const float* __restrict__ W,
                                            __bf16* __restrict__ Bt, int K, int N)
{
    __shared__ __bf16 T[64][72];
    const int k0 = blockIdx.x * 64, n0 = blockIdx.y * 64;
    const int t = threadIdx.x;
    #pragma unroll
    for (int i = 0; i < 4; ++i) {
        const int idx = t + i * 256;           // 0..1023
        const int r = idx >> 4, c4 = (idx & 15) * 4;
        const float4 v = *reinterpret_cast<const float4*>(&W[(size_t)(k0 + r) * N + n0 + c4]);
        T[c4 + 0][r] = (__bf16)v.x; T[c4 + 1][r] = (__bf16)v.y;
        T[c4 + 2][r] = (__bf16)v.z; T[c4 + 3][r] = (__bf16)v.w;
    }
    __syncthreads();
    #pragma unroll
    for (int i = 0; i < 2; ++i) {
        const int idx = t + i * 256;           // 0..511
        const int rr = idx >> 3, cc = (idx & 7) * 8;
        *reinterpret_cast<bf16x8*>(&Bt[(size_t)(n0 + rr) * K + k0 + cc]) =
            *reinterpret_cast<bf16x8*>(&T[rr][cc]);
    }
}

// =====================================================================
// K1: 256x256-tile 8-phase GEMM (unchanged — verified working).
// =====================================================================
__global__ __launch_bounds__(512, 2) void gemm8_k(const __bf16* __restrict__ A,
                                                  const __bf16* __restrict__ Bt,
                                                  float* __restrict__ C,
                                                  int N, int K)
{
    __shared__ __align__(16) __bf16 smem[65536];   // 128 KB
    const int tid = threadIdx.x, wave = tid >> 6, lane = tid & 63;
    const int l15 = lane & 15, l4 = lane >> 4;
    const int wr = wave >> 2, wc = wave & 3;

    const int nwg = gridDim.x;
    const int swz = (blockIdx.x & 7) * (nwg >> 3) + (blockIdx.x >> 3);
    const int NBN = N >> 8;
    const int bm = swz / NBN, bn = swz - bm * NBN;
    const int m0 = bm << 8, n0 = bn << 8;

    const int NKT = K >> 6;

    const int srow   = tid >> 2;                       // 0..127
    const int schunk = (tid & 3) ^ ((tid >> 3) & 3);
    const int sdst   = wave * 512;                     // elems

    const int achunk = l4 ^ ((l15 >> 1) & 3);
    const int aoff = (wr * 128 + l15) * 32 + achunk * 8;
    const int boff = (wc * 64  + l15) * 32 + achunk * 8;

    f32x4 acc[2][4][4] = {};
    bf16x8 af[4], bfr[4];

#define STAGE_SLAB(gb, r0, koff, slabptr) do {                                   \
        const __bf16* _g = (gb) + (size_t)((r0) + srow) * K + (koff) + schunk * 8; \
        gload16(_g,                    (slabptr) + sdst);                        \
        gload16(_g + (size_t)128 * K,  (slabptr) + sdst + 4096);                 \
    } while (0)

    STAGE_SLAB(A,  m0, 0,  smem);              // t0.A0
    STAGE_SLAB(Bt, n0, 0,  smem + 16384);      // t0.B0
    STAGE_SLAB(A,  m0, 32, smem + 8192);       // t0.A1
    STAGE_SLAB(Bt, n0, 32, smem + 24576);      // t0.B1
    STAGE_SLAB(A,  m0, 64, smem + 32768);          // t1.A0
    STAGE_SLAB(Bt, n0, 64, smem + 32768 + 16384);  // t1.B0
    asm volatile("s_waitcnt vmcnt(4)" ::: "memory");
    __builtin_amdgcn_s_barrier();

    #pragma unroll 1
    for (int T = 0; T < NKT; ++T) {
        __bf16* bufc = smem + (T & 1) * 32768;
        __bf16* bufn = smem + ((T & 1) ^ 1) * 32768;
        const int kt1 = (T + 1) * 64, kt2 = (T + 2) * 64;

        // ---- phase 1: khalf 0, mhalf 0 ----
        {
            const __bf16* As = bufc;
            const __bf16* Bs = bufc + 16384;
            #pragma unroll
            for (int f = 0; f < 4; ++f)  af[f]  = *reinterpret_cast<const bf16x8*>(As + aoff + f * 512);
            #pragma unroll
            for (int nf = 0; nf < 4; ++nf) bfr[nf] = *reinterpret_cast<const bf16x8*>(Bs + boff + nf * 512);
            if (T + 1 < NKT) STAGE_SLAB(A, m0, kt1 + 32, bufn + 8192);
            __builtin_amdgcn_s_barrier();
            __builtin_amdgcn_s_setprio(1);
            #pragma unroll
            for (int f = 0; f < 4; ++f)
                #pragma unroll
                for (int nf = 0; nf < 4; ++nf)
                    acc[0][f][nf] = mfma16(af[f], bfr[nf], acc[0][f][nf]);
            __builtin_amdgcn_s_setprio(0);
            __builtin_amdgcn_s_barrier();
        }
        // ---- phase 2: khalf 0, mhalf 1 ----
        {
            const __bf16* As = bufc;
            #pragma unroll
            for (int f = 0; f < 4; ++f)  af[f] = *reinterpret_cast<const bf16x8*>(As + aoff + 2048 + f * 512);
            if (T + 1 < NKT) STAGE_SLAB(Bt, n0, kt1 + 32, bufn + 24576);
            __builtin_amdgcn_s_barrier();
            __builtin_amdgcn_s_setprio(1);
            #pragma unroll
            for (int f = 0; f < 4; ++f)
                #pragma unroll
                for (int nf = 0; nf < 4; ++nf)
                    acc[1][f][nf] = mfma16(af[f], bfr[nf], acc[1][f][nf]);
            __builtin_amdgcn_s_setprio(0);
            __builtin_amdgcn_s_barrier();
        }
        // ---- phase 3: khalf 1, mhalf 0 ----
        {
            const __bf16* As = bufc + 8192;
            const __bf16* Bs = bufc + 24576;
            #pragma unroll
            for (int f = 0; f < 4; ++f)  af[f]  = *reinterpret_cast<const bf16x8*>(As + aoff + f * 512);
            #pragma unroll
            for (int nf = 0; nf < 4; ++nf) bfr[nf] = *reinterpret_cast<const bf16x8*>(Bs + boff + nf * 512);
            if (T + 2 < NKT) STAGE_SLAB(A, m0, kt2, bufc);
            __builtin_amdgcn_s_barrier();
            __builtin_amdgcn_s_setprio(1);
            #pragma unroll
            for (int f = 0; f < 4; ++f)
                #pragma unroll
                for (int nf = 0; nf < 4; ++nf)
                    acc[0][f][nf] = mfma16(af[f], bfr[nf], acc[0][f][nf]);
            __builtin_amdgcn_s_setprio(0);
            __builtin_amdgcn_s_barrier();
        }
        // ---- phase 4: khalf 1, mhalf 1 + boundary vmcnt ----
        {
            const __bf16* As = bufc + 8192;
            #pragma unroll
            for (int f = 0; f < 4; ++f)  af[f] = *reinterpret_cast<const bf16x8*>(As + aoff + 2048 + f * 512);
            if (T + 2 < NKT) STAGE_SLAB(Bt, n0, kt2, bufc + 16384);
            __builtin_amdgcn_s_barrier();
            __builtin_amdgcn_s_setprio(1);
            #pragma unroll
            for (int f = 0; f < 4; ++f)
                #pragma unroll
                for (int nf = 0; nf < 4; ++nf)
                    acc[1][f][nf] = mfma16(af[f], bfr[nf], acc[1][f][nf]);
            __builtin_amdgcn_s_setprio(0);
            if (T < NKT - 2) asm volatile("s_waitcnt vmcnt(4)" ::: "memory");
            else             asm volatile("s_waitcnt vmcnt(0)" ::: "memory");
            __builtin_amdgcn_s_barrier();
        }
    }
#undef STAGE_SLAB

    #pragma unroll
    for (int mh = 0; mh < 2; ++mh)
        #pragma unroll
        for (int f = 0; f < 4; ++f)
            #pragma unroll
            for (int nf = 0; nf < 4; ++nf)
                #pragma unroll
                for (int r = 0; r < 4; ++r) {
                    const int row = m0 + wr * 128 + mh * 64 + f * 16 + l4 * 4 + r;
                    const int col = n0 + wc * 64 + nf * 16 + l15;
                    C[(size_t)row * N + col] = acc[mh][f][nf][r];
                }
}

// =====================================================================
// K8: 128x256-tile 2-phase GEMM — same counted-vmcnt schedule, for the
// Wo projection (M=4096,N=2048 -> 256 blocks = full GPU vs 128 at 256²).
// 512 thr = 8 waves (2Mx4N), per-wave output 64x64. LDS 96 KB:
// 2 bufs x {A[128][32] 8K, A1 8K, B[256][32] 16K, B1 16K}.
// Per tile: 2 phases (khalf), 16 MFMA each. Stage map: ph1:(T+1).{A1,B1}
// [3 issues], ph2:(T+2).{A0,B0} [3 issues]; boundary vmcnt(3) keeps
// (T+2).A0B0 in flight, (T+1) fully landed. Prologue: T0 all + T1.A0B0,
// vmcnt(3). Requires M%128==0, N%256==0, K%64==0, grid%8==0.
// =====================================================================
__global__ __launch_bounds__(512, 2) void gemm8n_k(const __bf16* __restrict__ A,
                                                   const __bf16* __restrict__ Bt,
                                                   float* __restrict__ C,
                                                   int N, int K)
{
    __shared__ __align__(16) __bf16 smem[49152];   // 96 KB
    const int tid = threadIdx.x, wave = tid >> 6, lane = tid & 63;
    const int l15 = lane & 15, l4 = lane >> 4;
    const int wr = wave >> 2, wc = wave & 3;

    const int nwg = gridDim.x;
    const int swz = (blockIdx.x & 7) * (nwg >> 3) + (blockIdx.x >> 3);
    const int NBN = N >> 8;
    const int bm = swz / NBN, bn = swz - bm * NBN;
    const int m0 = bm << 7, n0 = bn << 8;

    const int NKT = K >> 6;

    const int srow   = tid >> 2;                       // 0..127
    const int schunk = (tid & 3) ^ ((tid >> 3) & 3);
    const int sdst   = wave * 512;                     // elems

    const int achunk = l4 ^ ((l15 >> 1) & 3);
    const int aoff = (wr * 64 + l15) * 32 + achunk * 8;   // + f*512 within A slab
    const int boff = (wc * 64 + l15) * 32 + achunk * 8;   // + nf*512 within B slab

    f32x4 acc[4][4] = {};
    bf16x8 af[4], bfr[4];

    // buffer b at b*24576 elems: A0 @0, A1 @4096, B0 @8192, B1 @16384
#define STAGE_A(koff, dstp) do {                                                  \
        gload16(A + (size_t)(m0 + srow) * K + (koff) + schunk * 8, (dstp) + sdst); \
    } while (0)
#define STAGE_B(koff, dstp) do {                                                  \
        const __bf16* _g = Bt + (size_t)(n0 + srow) * K + (koff) + schunk * 8;    \
        gload16(_g,                   (dstp) + sdst);                             \
        gload16(_g + (size_t)128 * K, (dstp) + sdst + 4096);                      \
    } while (0)

    STAGE_A(0,  smem);                 // T0.A0
    STAGE_B(0,  smem + 8192);          // T0.B0
    STAGE_A(32, smem + 4096);          // T0.A1
    STAGE_B(32, smem + 16384);         // T0.B1
    STAGE_A(64, smem + 24576);         // T1.A0
    STAGE_B(64, smem + 24576 + 8192);  // T1.B0
    asm volatile("s_waitcnt vmcnt(3)" ::: "memory");
    __builtin_amdgcn_s_barrier();

    #pragma unroll 1
    for (int T = 0; T < NKT; ++T) {
        __bf16* bufc = smem + (T & 1) * 24576;
        __bf16* bufn = smem + ((T & 1) ^ 1) * 24576;
        const int kt1 = (T + 1) * 64, kt2 = (T + 2) * 64;

        // ---- phase 1: khalf 0 ----
        {
            #pragma unroll
            for (int f = 0; f < 4; ++f)  af[f]  = *reinterpret_cast<const bf16x8*>(bufc + aoff + f * 512);
            #pragma unroll
            for (int nf = 0; nf < 4; ++nf) bfr[nf] = *reinterpret_cast<const bf16x8*>(bufc + 8192 + boff + nf * 512);
            if (T + 1 < NKT) { STAGE_A(kt1 + 32, bufn + 4096); STAGE_B(kt1 + 32, bufn + 16384); }
            __builtin_amdgcn_s_barrier();
            __builtin_amdgcn_s_setprio(1);
            #pragma unroll
            for (int f = 0; f < 4; ++f)
                #pragma unroll
                for (int nf = 0; nf < 4; ++nf)
                    acc[f][nf] = mfma16(af[f], bfr[nf], acc[f][nf]);
            __builtin_amdgcn_s_setprio(0);
            __builtin_amdgcn_s_barrier();
        }
        // ---- phase 2: khalf 1 + boundary vmcnt ----
        {
            #pragma unroll
            for (int f = 0; f < 4; ++f)  af[f]  = *reinterpret_cast<const bf16x8*>(bufc + 4096 + aoff + f * 512);
            #pragma unroll
            for (int nf = 0; nf < 4; ++nf) bfr[nf] = *reinterpret_cast<const bf16x8*>(bufc + 16384 + boff + nf * 512);
            if (T + 2 < NKT) { STAGE_A(kt2, bufc); STAGE_B(kt2, bufc + 8192); }
            __builtin_amdgcn_s_barrier();
            __builtin_amdgcn_s_setprio(1);
            #pragma unroll
            for (int f = 0; f < 4; ++f)
                #pragma unroll
                for (int nf = 0; nf < 4; ++nf)
                    acc[f][nf] = mfma16(af[f], bfr[nf], acc[f][nf]);
            __builtin_amdgcn_s_setprio(0);
            if (T < NKT - 2) asm volatile("s_waitcnt vmcnt(3)" ::: "memory");
            else             asm volatile("s_waitcnt vmcnt(0)" ::: "memory");
            __builtin_amdgcn_s_barrier();
        }
    }
#undef STAGE_A
#undef STAGE_B

    #pragma unroll
    for (int f = 0; f < 4; ++f)
        #pragma unroll
        for (int nf = 0; nf < 4; ++nf)
            #pragma unroll
            for (int r = 0; r < 4; ++r) {
                const int row = m0 + wr * 64 + f * 16 + l4 * 4 + r;
                const int col = n0 + wc * 64 + nf * 16 + l15;
                C[(size_t)row * N + col] = acc[f][nf][r];
            }
}

// =====================================================================
// K2: prep v3 — grid (SEQ/32, NKV, BATCH), 256 threads.
// =====================================================================
__global__ __launch_bounds__(256) void prep_k(const float* __restrict__ qkv,
                                              const float* __restrict__ norm_in,
                                              const int* __restrict__ pos_ids,
                                              __bf16* __restrict__ sq, __bf16* __restrict__ qr,
                                              __bf16* __restrict__ kr, __bf16* __restrict__ vt,
                                              float* __restrict__ nd, float* __restrict__ bnd,
                                              float* __restrict__ maxp)
{
    const int sc = blockIdx.x, kvh = blockIdx.y, b = blockIdx.z;
    const int s0 = sc * 32, t = threadIdx.x;
    const float scale = 0.08838834764831845f;      // 1/sqrt(128)
    const float s2 = scale * scale;
    const float NEG_LN_TH = -0.14391156831212787f; // -ln(10000)/64
    __shared__ float krn[32];

    // ---------- Q phase: 64 rows (2 heads x 32 s), 4 threads/row ----------
    {
        const int row = t >> 2;             // 0..63
        const int head = row >> 5, sl = row & 31;
        const int hq = kvh * 2 + head, nh = hq & 7;
        const int dq = (t & 3) * 16;        // pair-halves [dq,dq+16) & [dq+64,dq+80)
        const int pos = pos_ids[s0 + sl];
        const float* qp = qkv + (size_t)(b * SEQ + s0 + sl) * QKV_N + hq * 128;
        const float* np = norm_in + (b * NKV + nh) * 128;

        float x0[16], x1[16];
        #pragma unroll
        for (int i = 0; i < 16; i += 4) {
            *reinterpret_cast<float4*>(&x0[i]) = *reinterpret_cast<const float4*>(qp + dq + i);
            *reinterpret_cast<float4*>(&x1[i]) = *reinterpret_cast<const float4*>(qp + dq + 64 + i);
        }
        float nds = 0.f, qns = 0.f;
        bf16x8 sqv0[2], sqv1[2], qrv0[2], qrv1[2];
        #pragma unroll
        for (int i = 0; i < 16; ++i) {
            const int j = dq + i;           // 0..63
            float c, sn;
            __sincosf((float)pos * __expf((float)j * NEG_LN_TH), &sn, &c);
            qrv0[i >> 3][i & 7] = (__bf16)((x0[i] * c - x1[i] * sn) * scale);
            qrv1[i >> 3][i & 7] = (__bf16)((x1[i] * c + x0[i] * sn) * scale);
            const float sg0 = sigma_f(x0[i]), sg1 = sigma_f(x1[i]);
            sqv0[i >> 3][i & 7] = (__bf16)sg0;
            sqv1[i >> 3][i & 7] = (__bf16)sg1;
            nds += sg0 * np[j] + sg1 * np[j + 64];
            qns += (x0[i] * x0[i] + x1[i] * x1[i]) * s2;
        }
        __bf16* sqp = sq + ((size_t)(b * NH + hq) * SEQ + s0 + sl) * 128;
        __bf16* qrp = qr + ((size_t)(b * NH + hq) * SEQ + s0 + sl) * 128;
        *reinterpret_cast<bf16x8*>(sqp + dq)      = sqv0[0];
        *reinterpret_cast<bf16x8*>(sqp + dq + 8)  = sqv0[1];
        *reinterpret_cast<bf16x8*>(sqp + dq + 64) = sqv1[0];
        *reinterpret_cast<bf16x8*>(sqp + dq + 72) = sqv1[1];
        *reinterpret_cast<bf16x8*>(qrp + dq)      = qrv0[0];
        *reinterpret_cast<bf16x8*>(qrp + dq + 8)  = qrv0[1];
        *reinterpret_cast<bf16x8*>(qrp + dq + 64) = qrv1[0];
        *reinterpret_cast<bf16x8*>(qrp + dq + 72) = qrv1[1];

        nds += __shfl_xor(nds, 1); nds += __shfl_xor(nds, 2);
        qns += __shfl_xor(qns, 1); qns += __shfl_xor(qns, 2);
        if ((t & 3) == 0) {
            nd [(size_t)(b * NH + hq) * SEQ + s0 + sl] = nds;
            bnd[(size_t)(b * NH + hq) * SEQ + s0 + sl] = qns;
        }
    }

    // ---------- K phase: 32 rows, 4 threads/row (threads 0..127) ----------
    if (t < 128) {
        const int sl = t >> 2;
        const int dq = (t & 3) * 16;
        const int pos = pos_ids[s0 + sl];
        const float* kp = qkv + (size_t)(b * SEQ + s0 + sl) * QKV_N + 2048 + kvh * 128;
        float x0[16], x1[16];
        #pragma unroll
        for (int i = 0; i < 16; i += 4) {
            *reinterpret_cast<float4*>(&x0[i]) = *reinterpret_cast<const float4*>(kp + dq + i);
            *reinterpret_cast<float4*>(&x1[i]) = *reinterpret_cast<const float4*>(kp + dq + 64 + i);
        }
        bf16x8 kv0[2], kv1[2];
        float kns = 0.f;
        #pragma unroll
        for (int i = 0; i < 16; ++i) {
            const int j = dq + i;
            float c, sn;
            __sincosf((float)pos * __expf((float)j * NEG_LN_TH), &sn, &c);
            kv0[i >> 3][i & 7] = (__bf16)(x0[i] * c - x1[i] * sn);
            kv1[i >> 3][i & 7] = (__bf16)(x1[i] * c + x0[i] * sn);
            kns += x0[i] * x0[i] + x1[i] * x1[i];
        }
        __bf16* krp = kr + ((size_t)(b * NKV + kvh) * SEQ + s0 + sl) * 128;
        *reinterpret_cast<bf16x8*>(krp + dq)      = kv0[0];
        *reinterpret_cast<bf16x8*>(krp + dq + 8)  = kv0[1];
        *reinterpret_cast<bf16x8*>(krp + dq + 64) = kv1[0];
        *reinterpret_cast<bf16x8*>(krp + dq + 72) = kv1[1];
        kns += __shfl_xor(kns, 1); kns += __shfl_xor(kns, 2);
        if ((t & 3) == 0) krn[sl] = kns;
    }

    // ---------- V phase: transpose via LDS, coalesced vt writes ----------
    __shared__ float vl[128][33];
    {
        const int sl = t >> 3, dch = (t & 7) * 16;
        const float* vp = qkv + (size_t)(b * SEQ + s0 + sl) * QKV_N + 3072 + kvh * 128 + dch;
        float xv[16];
        #pragma unroll
        for (int i = 0; i < 16; i += 4)
            *reinterpret_cast<float4*>(&xv[i]) = *reinterpret_cast<const float4*>(vp + i);
        #pragma unroll
        for (int i = 0; i < 16; ++i) vl[dch + i][sl] = xv[i];
    }
    __syncthreads();
    if (t == 0) {
        float mx = 0.f;
        #pragma unroll
        for (int i = 0; i < 32; ++i) mx = fmaxf(mx, krn[i]);
        maxp[((b * NKV + kvh) << 6) + sc] = mx;
    }
    {
        const int d = t >> 1, sh = (t & 1) * 16;
        bf16x8 o0, o1;
        #pragma unroll
        for (int j = 0; j < 8; ++j) o0[j] = (__bf16)vl[d][sh + j];
        #pragma unroll
        for (int j = 0; j < 8; ++j) o1[j] = (__bf16)vl[d][sh + 8 + j];
        __bf16* vp = vt + ((size_t)((b * NKV + kvh) * 128 + d)) * SEQ + s0 + sh;
        *reinterpret_cast<bf16x8*>(vp)     = o0;
        *reinterpret_cast<bf16x8*>(vp + 8) = o1;
    }
}

// =====================================================================
// K3: memory_output = (sigma_q @ mem) / nd, write g*val into combined
// =====================================================================
__global__ __launch_bounds__(256) void memout_k(const __bf16* __restrict__ sq,
                                                const float* __restrict__ mem_in,
                                                const float* __restrict__ nd,
                                                const float* __restrict__ gate,
                                                __bf16* __restrict__ cb)
{
    __shared__ __align__(16) __bf16 mt[128][136];   // mem^T [e][d]
    const int tid = threadIdx.x;
    const int h = blockIdx.y, b = blockIdx.z;
    const int s0 = blockIdx.x * 64;

    const float* mem = mem_in + (size_t)(b * NKV + (h & 7)) * 16384;
    for (int i = tid; i < 16384; i += 256) {
        int dd = i >> 7, e = i & 127;
        mt[e][dd] = (__bf16)mem[i];
    }
    __syncthreads();

    const int wave = tid >> 6, lane = tid & 63, l15 = lane & 15, l4 = lane >> 4;
    f32x4 acc[8] = {};
    const __bf16* sqb = sq + ((size_t)(b * NH + h) * SEQ + s0 + wave * 16 + l15) * 128;
    #pragma unroll
    for (int kb = 0; kb < 4; ++kb) {
        bf16x8 a = *reinterpret_cast<const bf16x8*>(sqb + kb * 32 + l4 * 8);
        #pragma unroll
        for (int nc = 0; nc < 8; ++nc) {
            bf16x8 bb = *reinterpret_cast<bf16x8*>(&mt[nc * 16 + l15][kb * 32 + l4 * 8]);
            acc[nc] = mfma16(a, bb, acc[nc]);
        }
    }
    float g = 1.f / (1.f + __expf(-gate[h]));
    #pragma unroll
    for (int r = 0; r < 4; ++r) {
        int srow = s0 + wave * 16 + l4 * 4 + r;
        float scl = g / nd[(size_t)(b * NH + h) * SEQ + srow];
        __bf16* cbp = cb + (size_t)(b * SEQ + srow) * HID + h * 128;
        #pragma unroll
        for (int nc = 0; nc < 8; ++nc)
            cbp[nc * 16 + l15] = (__bf16)(acc[nc][r] * scl);
    }
}

// =====================================================================
// K5: updated_memory partials + sigma_k column-sum partials.
// =====================================================================
__global__ __launch_bounds__(256) void memupd_k(const float* __restrict__ qkv,
                                                float* __restrict__ part,
                                                float* __restrict__ npart)
{
    const int sp = blockIdx.x, h = blockIdx.y, b = blockIdx.z;
    const int tid = threadIdx.x;
    const int tx = tid & 15, ty = tid >> 4;   // d-block tx*8, e-block ty*8
    __shared__ __align__(16) float sk[8][128];
    __shared__ __align__(16) float sv[8][128];
    float acc[8][8] = {};
    float nacc = 0.f;                          // threads 0..127: sum_s sigma_k[.,tid]

    const int s0 = sp * (SEQ / NSPLIT);
    for (int so = 0; so < SEQ / NSPLIT; so += 8) {
        for (int i = tid; i < 8 * 128; i += 256) {
            int rr = i >> 7, dd = i & 127;
            const float* rowp = qkv + (size_t)(b * SEQ + s0 + so + rr) * QKV_N;
            sk[rr][dd] = sigma_f(rowp[2048 + h * 128 + dd]);
            sv[rr][dd] = rowp[3072 + h * 128 + dd];
        }
        __syncthreads();
        if (tid < 128) {
            #pragma unroll
            for (int rr = 0; rr < 8; ++rr) nacc += sk[rr][tid];
        }
        #pragma unroll
        for (int rr = 0; rr < 8; ++rr) {
            float4 k0 = *reinterpret_cast<float4*>(&sk[rr][tx * 8]);
            float4 k1 = *reinterpret_cast<float4*>(&sk[rr][tx * 8 + 4]);
            float4 v0 = *reinterpret_cast<float4*>(&sv[rr][ty * 8]);
            float4 v1 = *reinterpret_cast<float4*>(&sv[rr][ty * 8 + 4]);
            float kreg[8] = {k0.x,k0.y,k0.z,k0.w,k1.x,k1.y,k1.z,k1.w};
            float vreg[8] = {v0.x,v0.y,v0.z,v0.w,v1.x,v1.y,v1.z,v1.w};
            #pragma unroll
            for (int i = 0; i < 8; ++i)
                #pragma unroll
                for (int j2 = 0; j2 < 8; ++j2)
                    acc[i][j2] += kreg[i] * vreg[j2];
        }
        __syncthreads();
    }
    float* pb = part + ((size_t)sp * (BATCH * NKV) + b * NKV + h) * 16384;
    #pragma unroll
    for (int i = 0; i < 8; ++i)
        #pragma unroll
        for (int j2 = 0; j2 < 8; ++j2)
            pb[(tx * 8 + i) * 128 + ty * 8 + j2] = acc[i][j2];
    if (tid < 128)
        npart[((size_t)sp * (BATCH * NKV) + b * NKV + h) * 128 + tid] = nacc;
}

// =====================================================================
// K6: fused reduce — [0,1024) mem partials + mem_in ; [1024,1040) norm.
// =====================================================================
__global__ __launch_bounds__(256) void memrednorm_k(const float* __restrict__ part,
                                                    const float* __restrict__ mem_in,
                                                    float* __restrict__ out_mem,
                                                    const float* __restrict__ npart,
                                                    const float* __restrict__ norm_in,
                                                    float* __restrict__ out_norm)
{
    const int bid = blockIdx.x;
    if (bid < 1024) {
        const size_t i = (size_t)bid * 256 + threadIdx.x;   // 262144 total
        float a = mem_in[i];
        #pragma unroll
        for (int sp = 0; sp < NSPLIT; ++sp) a += part[(size_t)sp * 262144 + i];
        out_mem[i] = a;
    } else if (threadIdx.x < 128) {
        const int bh = bid - 1024, d = threadIdx.x;
        float a = norm_in[bh * 128 + d];
        #pragma unroll
        for (int sp = 0; sp < NSPLIT; ++sp)
            a += npart[((size_t)sp * (BATCH * NKV) + bh) * 128 + d];
        out_norm[bh * 128 + d] = a;
    }
}

// =====================================================================
// K7: flash causal attention v6 = v5 structure with plds RE-SWIZZLED
// (v5's linear plds made the P b128-read a 16-way bank conflict:
//  conflicts 4.3M -> 8.1M; revert to v4's chunk^=(row&7) layout).
// =====================================================================
__global__ __launch_bounds__(256, 2) void attn_k(const __bf16* __restrict__ qr,
                                                 const __bf16* __restrict__ kr,
                                                 const __bf16* __restrict__ vt,
                                                 const float* __restrict__ gate,
                                                 const float* __restrict__ bnd,
                                                 const float* __restrict__ maxp,
                                                 __bf16* __restrict__ cb)
{
    __shared__ __align__(16) char smem[81920];
    char* ksB = smem;                        // K swz [128][128] bf16 (32 KB)
    char* vsB = smem + 32768;                // V^T swz [128][128]    (32 KB)
    char* pB  = smem + 65536;                // plds 4 x [32][64] swz (16 KB)
    float*  red  = (float*)smem;             // epilogue overlay
    float*  lred = (float*)(smem + 65536);   // epilogue overlay

    const int tid = threadIdx.x, wave = tid >> 6, lane = tid & 63;
    const int l15 = lane & 15, l4 = lane >> 4;
    const int e3 = l15 & 7, e2 = e3 >> 2;
    const int ksub = wave >> 1;                        // k-subtile parity
    const int wq   = wave & 1;                         // q 32-row half

    // ---- XCD swizzle: each XCD owns 2 full (b,kvh) groups ----
    const int n   = blockIdx.x + 16 * (blockIdx.y + 16 * blockIdx.z);
    const int xcd = n & 7, i64 = n >> 3;
    const int grp = xcd * 2 + (i64 >> 5);
    const int within = i64 & 31;
    const int b   = grp >> 3;
    const int kvh = grp & 7;
    const int h   = kvh * 2 + (within >> 4);
    const int x   = within & 15;

    const __bf16* kbase = kr + (size_t)(b * NKV + kvh) * SEQ * 128;
    const __bf16* vbase = vt + (size_t)(b * NKV + kvh) * 128 * SEQ;
    const float* bbase  = bnd + (size_t)(b * NH + h) * SEQ;

    const float g  = 1.f / (1.f + __expf(-gate[h]));
    const float gi = 1.f - g;
    float kn2 = 0.f;
    const float* mp = maxp + (b * NKV + kvh) * 64;
    #pragma unroll
    for (int i = 0; i < 64; i += 4) {
        const float4 v = *reinterpret_cast<const float4*>(mp + i);
        kn2 = fmaxf(kn2, fmaxf(fmaxf(v.x, v.y), fmaxf(v.z, v.w)));
    }
    const float knmax = sqrtf(kn2);

    bf16x8 ones;
    #pragma unroll
    for (int j = 0; j < 8; ++j) ones[j] = (__bf16)1.0f;

    // ---- staging addresses (bytes): LDS row r chunk c <- global chunk c^(r&7) ----
    const int srow = wave * 32 + l4;                   // + j*4 per issue
    const int chA  = (lane & 15) ^ l4;
    const char* KG0 = (const char*)kbase + srow * 256 + chA * 16;          // j even
    const char* KG1 = (const char*)kbase + srow * 256 + ((chA ^ 4) * 16);  // j odd
    const char* VG0 = (const char*)vbase + srow * 4096 + chA * 16;
    const char* VG1 = (const char*)vbase + srow * 4096 + ((chA ^ 4) * 16);
    __bf16* kdst = (__bf16*)(ksB + wave * 8192);
    __bf16* vdst = (__bf16*)(vsB + wave * 8192);

    // ---- K/V read bases (byte offsets; XOR split into fields) ----
    const int t16 = (l4 ^ (e3 & 3)) * 16;
    const int KBe = l15 * 256 + ksub * 16384 + t16 + e2 * 64;
    const int KBo = l15 * 256 + ksub * 16384 + t16 + (1 ^ e2) * 64;
    const int VB0 = l15 * 256 + t16 + e2 * 64 + ksub * 128;
    const int VB1 = l15 * 256 + t16 + (1 ^ e2) * 64 + ksub * 128;
    // plds swizzled (v4 layout): write chunk = ((sub*2+(l15>>3)) ^ (row&7)),
    // read base PR: row=l15, chunk = l4 ^ (l15&7); partner chunk = ^4 -> byte^64.
    const int PWb = wave * 4096 + (l15 & 7) * 2;       // + row*128 + chunk*16
    const int PR  = wave * 4096 + l15 * 128 + ((l4 ^ e3) * 16);

#define ISSUE_K(ktrow) do {                                                      \
        const int _ko = (ktrow) * 256;                                           \
        _Pragma("unroll")                                                        \
        for (int _j = 0; _j < 8; ++_j)                                           \
            gload16((const __bf16*)(((_j & 1) ? KG1 : KG0) + _ko + _j * 1024),   \
                    kdst + _j * 512);                                            \
    } while (0)
#define ISSUE_V(ktrow) do {                                                      \
        const int _vo = (ktrow) * 2;                                             \
        _Pragma("unroll")                                                        \
        for (int _j = 0; _j < 8; ++_j)                                           \
            gload16((const __bf16*)(((_j & 1) ? VG1 : VG0) + _vo + _j * 16384),  \
                    vdst + _j * 512);                                            \
    } while (0)

    #pragma unroll 1
    for (int tile = 0; tile < 2; ++tile) {
        const int q0 = (tile == 0 ? x : 31 - x) * 64;
        const int qw = q0 + wq * 32;
        const int NT = (q0 >> 6) + 1;                  // # 64-kt subtiles
        const int NI = (NT + 1) >> 1;                  // 128-kt iterations

        bf16x8 af[2][4];
        float m_r[2][4];
        #pragma unroll
        for (int m = 0; m < 2; ++m) {
            const __bf16* qb = qr + ((size_t)(b * NH + h) * SEQ + qw + m * 16 + l15) * 128;
            #pragma unroll
            for (int kb = 0; kb < 4; ++kb)
                af[m][kb] = *reinterpret_cast<const bf16x8*>(qb + kb * 32 + l4 * 8);
            #pragma unroll
            for (int r = 0; r < 4; ++r)
                m_r[m][r] = sqrtf(bbase[qw + m * 16 + l4 * 4 + r]) * knmax + 1.0f;
        }

        f32x4 o0[8] = {}, o1[8] = {};
        f32x4 lc0 = {}, lc1 = {};

        // ---- prologue: stage iter-0 K and V ----
        ISSUE_K(0);
        ISSUE_V(0);
        asm volatile("s_waitcnt vmcnt(8)" ::: "memory");   // K(0) landed
        __builtin_amdgcn_sched_barrier(0);
        __builtin_amdgcn_s_barrier();

        #pragma unroll 1
        for (int it = 0; it < NI; ++it) {
            const int s = 2 * it + ksub;
            const bool act  = (s < NT);
            const bool more = (it + 1 < NI);

            f32x4 s0[4] = {}, s1[4] = {};
            if (act) {
                __builtin_amdgcn_s_setprio(1);
                #pragma unroll
                for (int kb = 0; kb < 4; ++kb) {
                    const int kbb = ((kb & 1) ? KBo : KBe) + (kb >> 1) * 128;
                    #pragma unroll
                    for (int sub = 0; sub < 4; ++sub) {
                        bf16x8 bb = *reinterpret_cast<const bf16x8*>(ksB + kbb + sub * 4096);
                        s0[sub] = mfma16(af[0][kb], bb, s0[sub]);
                        s1[sub] = mfma16(af[1][kb], bb, s1[sub]);
                    }
                }
                __builtin_amdgcn_s_setprio(0);
            }
            __builtin_amdgcn_sched_barrier(0);
            __builtin_amdgcn_s_barrier();              // (1) all done reading Ks(it)

            if (more) ISSUE_K((it + 1) * 128);

            if (act) {
                // ---- exp + causal mask + swizzled plds store ----
                #pragma unroll
                for (int r = 0; r < 4; ++r) {
                    const int q0r = qw + l4 * 4 + r;
                    const int q1r = q0r + 16;
                    const int p0r = l4 * 4 + r;
                    const int rw0 = PWb + p0r * 128;
                    #pragma unroll
                    for (int sub = 0; sub < 4; ++sub) {
                        const int key = s * 64 + sub * 16 + l15;
                        float p0 = __expf(s0[sub][r] - m_r[0][r]);
                        float p1 = __expf(s1[sub][r] - m_r[1][r]);
                        p0 = (key <= q0r) ? p0 : 0.f;
                        p1 = (key <= q1r) ? p1 : 0.f;
                        const int cc = (sub * 2 + (l15 >> 3)) ^ (p0r & 7);
                        *(__bf16*)(pB + rw0 + cc * 16)        = (__bf16)p0;
                        *(__bf16*)(pB + rw0 + cc * 16 + 2048) = (__bf16)p1;
                    }
                }
            }
            if (more) asm volatile("s_waitcnt vmcnt(8)" ::: "memory");  // V(it) landed
            else      asm volatile("s_waitcnt vmcnt(0)" ::: "memory");
            __builtin_amdgcn_sched_barrier(0);
            __builtin_amdgcn_s_barrier();              // (2) Vs(it) visible

            if (act) {
                // ---- swizzled P reads + PV ----
                bf16x8 a00 = *reinterpret_cast<const bf16x8*>(pB + PR);
                bf16x8 a01 = *reinterpret_cast<const bf16x8*>(pB + (PR ^ 64));
                bf16x8 a10 = *reinterpret_cast<const bf16x8*>(pB + PR + 2048);
                bf16x8 a11 = *reinterpret_cast<const bf16x8*>(pB + (PR ^ 64) + 2048);
                __builtin_amdgcn_s_setprio(1);
                lc0 = mfma16(a00, ones, lc0); lc0 = mfma16(a01, ones, lc0);
                lc1 = mfma16(a10, ones, lc1); lc1 = mfma16(a11, ones, lc1);
                #pragma unroll
                for (int nc = 0; nc < 8; ++nc) {
                    bf16x8 b0 = *reinterpret_cast<const bf16x8*>(vsB + VB0 + nc * 4096);
                    bf16x8 b1 = *reinterpret_cast<const bf16x8*>(vsB + VB1 + nc * 4096);
                    o0[nc] = mfma16(a00, b0, o0[nc]); o0[nc] = mfma16(a01, b1, o0[nc]);
                    o1[nc] = mfma16(a10, b0, o1[nc]); o1[nc] = mfma16(a11, b1, o1[nc]);
                }
                __builtin_amdgcn_s_setprio(0);
            }
            __builtin_amdgcn_sched_barrier(0);
            __builtin_amdgcn_s_barrier();              // (3) all done reading Vs(it)

            if (more) {
                ISSUE_V((it + 1) * 128);
                asm volatile("s_waitcnt vmcnt(8)" ::: "memory");        // K(it+1) landed
            } else {
                asm volatile("s_waitcnt vmcnt(0)" ::: "memory");
            }
            __builtin_amdgcn_sched_barrier(0);
            __builtin_amdgcn_s_barrier();              // (4) Ks(it+1) visible
        }

        // ---- cross-pair reduction: wave w+2 -> wave w (same q-rows) ----
        if (wave >= 2) {
            float* rb = red + (wave - 2) * 4224;       // 32 rows x stride 132
            #pragma unroll
            for (int nc = 0; nc < 8; ++nc)
                #pragma unroll
                for (int r = 0; r < 4; ++r) {
                    rb[(l4 * 4 + r) * 132 + nc * 16 + l15]        = o0[nc][r];
                    rb[(16 + l4 * 4 + r) * 132 + nc * 16 + l15]   = o1[nc][r];
                }
            if (l15 == 0) {
                float* lb = lred + (wave - 2) * 32;
                #pragma unroll
                for (int r = 0; r < 4; ++r) {
                    lb[l4 * 4 + r]      = lc0[r];
                    lb[16 + l4 * 4 + r] = lc1[r];
                }
            }
        }
        __syncthreads();
        if (wave < 2) {
            float* rb = red + wave * 4224;
            const float* lb = lred + wave * 32;
            #pragma unroll
            for (int r = 0; r < 4; ++r) {
                const int qrow = qw + l4 * 4 + r;
                const float i0 = gi / (lc0[r] + lb[l4 * 4 + r]);
                const float i1 = gi / (lc1[r] + lb[16 + l4 * 4 + r]);
                __bf16* c0 = cb + (size_t)(b * SEQ + qrow) * HID + h * 128;
                __bf16* c1 = cb + (size_t)(b * SEQ + qrow + 16) * HID + h * 128;
                #pragma unroll
                for (int nc = 0; nc < 8; ++nc) {
                    const int dd = nc * 16 + l15;
                    const float v0 = o0[nc][r] + rb[(l4 * 4 + r) * 132 + dd];
                    const float v1 = o1[nc][r] + rb[(16 + l4 * 4 + r) * 132 + dd];
                    c0[dd] = (__bf16)((float)c0[dd] + v0 * i0);
                    c1[dd] = (__bf16)((float)c1[dd] + v1 * i1);
                }
            }
        }
        __syncthreads();   // red/lred overlay dead before next tile restages Ks
    }
#undef ISSUE_K
#undef ISSUE_V
}

// =====================================================================
extern "C" void kernel_launch(void* const* d_in, const int* in_sizes, int n_in,
                              void* d_out, int out_size, void* d_ws, size_t ws_size,
                              hipStream_t stream)
{
    const float* hidden  = (const float*)d_in[0];
    const float* Wq      = (const float*)d_in[1];
    const float* Wk      = (const float*)d_in[2];
    const float* Wv      = (const float*)d_in[3];
    const float* Wo      = (const float*)d_in[4];
    const float* gate    = (const float*)d_in[5];
    const float* mem_in  = (const float*)d_in[6];
    const float* norm_in = (const float*)d_in[7];
    const int*   pos     = (const int*)d_in[8];

    float* out_final = (float*)d_out;                  // (B,S,HID)
    float* out_mem   = out_final + (size_t)BATCH * SEQ * HID;     // (B,8,128,128)
    float* out_norm  = out_mem + (size_t)BATCH * NKV * 128 * 128; // (B,8,1,128)

    char* ws = (char*)d_ws;
    float*  qkv  = (float*)(ws + OFF_QKV);
    __bf16* sq   = (__bf16*)(ws + OFF_SQ);
    __bf16* qrb  = (__bf16*)(ws + OFF_QR);
    __bf16* krb  = (__bf16*)(ws + OFF_KR);
    __bf16* vtb  = (__bf16*)(ws + OFF_VT);
    float*  nd   = (float*)(ws + OFF_ND);
    __bf16* cb   = (__bf16*)(ws + OFF_CB);
    float*  part = (float*)(ws + OFF_PART);
    float*  bnd  = (float*)(ws + OFF_BND);
    float*  maxp = (float*)(ws + OFF_MAXP);
    float*  npart = (float*)(ws + OFF_NPART);
    // overlays (lifetimes disjoint from the named owners):
    __bf16* hb   = (__bf16*)(ws + OFF_SQ);    // bf16 hidden  [4096][2048], dead after gemm1
    __bf16* qkvT = (__bf16*)(ws + OFF_QR);    // bf16 W_qkv^T [4096][2048], dead after gemm1
    __bf16* woT  = (__bf16*)(ws + OFF_PART);  // bf16 Wo^T    [2048][2048], after memrednorm

    // 0. fused pre-pass: hidden f2b + Wq/Wk/Wv transposes (1 launch)
    pre_k<<<6144, 256, 0, stream>>>(hidden, Wq, Wk, Wv, hb, qkvT);

    // 1. fused QKV projection: [4096 x 2048] @ [2048 x 4096], 256 blocks (1/CU)
    gemm8_k<<<(M_ROWS / 256) * (QKV_N / 256), 512, 0, stream>>>(hb, qkvT, qkv, QKV_N, HID);

    // 2. prep (overwrites hb/qkvT — now dead); k-norm maxima fused in
    prep_k<<<dim3(SEQ / 32, NKV, BATCH), 256, 0, stream>>>(qkv, norm_in, pos, sq, qrb, krb, vtb,
                                                           nd, bnd, maxp);

    // 3. memory_output -> combined (g * memout / nd)
    memout_k<<<dim3(SEQ / 64, NH, BATCH), 256, 0, stream>>>(sq, mem_in, nd, gate, cb);

    // 4/5. updated_memory (+ sigma_k col-sum partials) and fused reduce
    memupd_k<<<dim3(NSPLIT, NKV, BATCH), 256, 0, stream>>>(qkv, part, npart);
    memrednorm_k<<<1040, 256, 0, stream>>>(part, mem_in, out_mem, npart, norm_in, out_norm);

    // 6b. Wo^T (overlays part — dead after memrednorm)
    tr_k<<<dim3(HID / 64, HID / 64), 256, 0, stream>>>(Wo, woT, HID, HID);

    // 7. causal attention v6 (v5 + restored plds swizzle)
    attn_k<<<dim3(16, NH, BATCH), 256, 0, stream>>>(qrb, krb, vtb, gate, bnd, maxp, cb);

    // 8. output projection: [4096 x 2048] @ [2048 x 2048], 128x256 tiles -> 256 blocks
    gemm8n_k<<<(M_ROWS / 128) * (HID / 256), 512, 0, stream>>>(cb, woT, out_final, HID, HID);
}

// Round 5
// 426.378 us; speedup vs baseline: 1.1029x; 1.0321x over previous
//
#include <hip/hip_runtime.h>

// ---------- problem constants ----------
#define BATCH 2
#define SEQ   2048
#define HID   2048
#define NH    16
#define NKV   8
#define HD    128
#define M_ROWS (BATCH * SEQ)          // 4096
#define QKV_N  4096                   // 2048 q | 1024 k | 1024 v

typedef __attribute__((ext_vector_type(8))) __bf16 bf16x8;
typedef __attribute__((ext_vector_type(4))) float  f32x4;

static __device__ __forceinline__ f32x4 mfma16(bf16x8 a, bf16x8 b, f32x4 c) {
    return __builtin_amdgcn_mfma_f32_16x16x32_bf16(a, b, c, 0, 0, 0);
}
static __device__ __forceinline__ float sigma_f(float x) {
    return x > 0.f ? x + 1.f : __expf(x);   // elu(x)+1
}
// async global->LDS, 16B per lane; lds base must be wave-uniform
static __device__ __forceinline__ void gload16(const __bf16* g, __bf16* l) {
    __builtin_amdgcn_global_load_lds(
        (const __attribute__((address_space(1))) void*)g,
        (__attribute__((address_space(3))) void*)l, 16, 0, 0);
}

// ---------- workspace layout (bytes) ----------
#define OFF_QKV  0ull                              // float [4096][4096]   64 MB
#define OFF_SQ   67108864ull                       // bf16  (b,h,S,128)    16 MB  (pre-GEMM: hb)
#define OFF_QR   83886080ull                       // bf16  (b,h,S,128)    16 MB  (pre-GEMM: qkvT)
#define OFF_KR   100663296ull                      // bf16  (b,kvh,S,128)   8 MB
#define OFF_VT   109051904ull                      // bf16  (b,kvh,128,S)   8 MB
#define OFF_ND   117440512ull                      // float (b,h,S)       256 KB
#define OFF_CB   117702656ull                      // bf16  [4096][2048]   16 MB
#define OFF_PART 134479872ull                      // float 8*(b,kvh,128,128) 8 MB (late: woT 8 MB)
#define OFF_BND  142868480ull                      // float (b,h,S)       256 KB  (q row-norm^2)
#define OFF_MAXP 143130624ull                      // float (b,kvh,64)     4 KB   (k-norm^2 chunk max)
#define OFF_NPART 143134720ull                     // float 8*(b,kvh,128)  64 KB  (sigma_k col-sum partials)
#define NSPLIT 8

// =====================================================================
// K0: fused pre-pass — f2b (hidden fp32->bf16) + Wq/Wk/Wv transposes.
// grid: [0,4096) f2b ; [4096,5120) Wq ; [5120,5632) Wk ; [5632,6144) Wv
// =====================================================================
__global__ __launch_bounds__(256) void pre_k(const float* __restrict__ hidden,
                                             const float* __restrict__ Wq,
                                             const float* __restrict__ Wk,
                                             const float* __restrict__ Wv,
                                             __bf16* __restrict__ hb,
                                             __bf16* __restrict__ qkvT)
{
    __shared__ __bf16 T[64][72];
    const int bid = blockIdx.x;
    const int t = threadIdx.x;
    if (bid < 4096) {
        const size_t i = ((size_t)bid * 256 + t) * 8;
        const float4 v0 = *reinterpret_cast<const float4*>(hidden + i);
        const float4 v1 = *reinterpret_cast<const float4*>(hidden + i + 4);
        bf16x8 o;
        o[0]=(__bf16)v0.x; o[1]=(__bf16)v0.y; o[2]=(__bf16)v0.z; o[3]=(__bf16)v0.w;
        o[4]=(__bf16)v1.x; o[5]=(__bf16)v1.y; o[6]=(__bf16)v1.z; o[7]=(__bf16)v1.w;
        *reinterpret_cast<bf16x8*>(hb + i) = o;
        return;
    }
    int tb = bid - 4096;
    const float* W; __bf16* Bt; int N;
    if (tb < 1024)      { W = Wq; Bt = qkvT;                         N = 2048; }
    else if (tb < 1536) { W = Wk; Bt = qkvT + (size_t)2048 * HID;    N = 1024; tb -= 1024; }
    else                { W = Wv; Bt = qkvT + (size_t)3072 * HID;    N = 1024; tb -= 1536; }
    const int k0 = (tb & 31) * 64, n0 = (tb >> 5) * 64;
    #pragma unroll
    for (int i = 0; i < 4; ++i) {
        const int idx = t + i * 256;
        const int r = idx >> 4, c4 = (idx & 15) * 4;
        const float4 v = *reinterpret_cast<const float4*>(&W[(size_t)(k0 + r) * N + n0 + c4]);
        T[c4 + 0][r] = (__bf16)v.x; T[c4 + 1][r] = (__bf16)v.y;
        T[c4 + 2][r] = (__bf16)v.z; T[c4 + 3][r] = (__bf16)v.w;
    }
    __syncthreads();
    #pragma unroll
    for (int i = 0; i < 2; ++i) {
        const int idx = t + i * 256;
        const int rr = idx >> 3, cc = (idx & 7) * 8;
        *reinterpret_cast<bf16x8*>(&Bt[(size_t)(n0 + rr) * HID + k0 + cc]) =
            *reinterpret_cast<bf16x8*>(&T[rr][cc]);
    }
}

// =====================================================================
// K0b: W fp32 [K][N] -> Bt bf16 [N][K]  (64x64 LDS tile transpose) — Wo only
// =====================================================================
__global__ __launch_bounds__(256) void tr_k(const float* __restrict__ W,
                                            __bf16* __restrict__ Bt, int K, int N)
{
    __shared__ __bf16 T[64][72];
    const int k0 = blockIdx.x * 64, n0 = blockIdx.y * 64;
    const int t = threadIdx.x;
    #pragma unroll
    for (int i = 0; i < 4; ++i) {
        const int idx = t + i * 256;           // 0..1023
        const int r = idx >> 4, c4 = (idx & 15) * 4;
        const float4 v = *reinterpret_cast<const float4*>(&W[(size_t)(k0 + r) * N + n0 + c4]);
        T[c4 + 0][r] = (__bf16)v.x; T[c4 + 1][r] = (__bf16)v.y;
        T[c4 + 2][r] = (__bf16)v.z; T[c4 + 3][r] = (__bf16)v.w;
    }
    __syncthreads();
    #pragma unroll
    for (int i = 0; i < 2; ++i) {
        const int idx = t + i * 256;           // 0..511
        const int rr = idx >> 3, cc = (idx & 7) * 8;
        *reinterpret_cast<bf16x8*>(&Bt[(size_t)(n0 + rr) * K + k0 + cc]) =
            *reinterpret_cast<bf16x8*>(&T[rr][cc]);
    }
}

// =====================================================================
// K1: 256x256-tile 8-phase GEMM (unchanged — verified working).
// =====================================================================
__global__ __launch_bounds__(512, 2) void gemm8_k(const __bf16* __restrict__ A,
                                                  const __bf16* __restrict__ Bt,
                                                  float* __restrict__ C,
                                                  int N, int K)
{
    __shared__ __align__(16) __bf16 smem[65536];   // 128 KB
    const int tid = threadIdx.x, wave = tid >> 6, lane = tid & 63;
    const int l15 = lane & 15, l4 = lane >> 4;
    const int wr = wave >> 2, wc = wave & 3;

    const int nwg = gridDim.x;
    const int swz = (blockIdx.x & 7) * (nwg >> 3) + (blockIdx.x >> 3);
    const int NBN = N >> 8;
    const int bm = swz / NBN, bn = swz - bm * NBN;
    const int m0 = bm << 8, n0 = bn << 8;

    const int NKT = K >> 6;

    const int srow   = tid >> 2;                       // 0..127
    const int schunk = (tid & 3) ^ ((tid >> 3) & 3);
    const int sdst   = wave * 512;                     // elems

    const int achunk = l4 ^ ((l15 >> 1) & 3);
    const int aoff = (wr * 128 + l15) * 32 + achunk * 8;
    const int boff = (wc * 64  + l15) * 32 + achunk * 8;

    f32x4 acc[2][4][4] = {};
    bf16x8 af[4], bfr[4];

#define STAGE_SLAB(gb, r0, koff, slabptr) do {                                   \
        const __bf16* _g = (gb) + (size_t)((r0) + srow) * K + (koff) + schunk * 8; \
        gload16(_g,                    (slabptr) + sdst);                        \
        gload16(_g + (size_t)128 * K,  (slabptr) + sdst + 4096);                 \
    } while (0)

    STAGE_SLAB(A,  m0, 0,  smem);              // t0.A0
    STAGE_SLAB(Bt, n0, 0,  smem + 16384);      // t0.B0
    STAGE_SLAB(A,  m0, 32, smem + 8192);       // t0.A1
    STAGE_SLAB(Bt, n0, 32, smem + 24576);      // t0.B1
    STAGE_SLAB(A,  m0, 64, smem + 32768);          // t1.A0
    STAGE_SLAB(Bt, n0, 64, smem + 32768 + 16384);  // t1.B0
    asm volatile("s_waitcnt vmcnt(4)" ::: "memory");
    __builtin_amdgcn_s_barrier();

    #pragma unroll 1
    for (int T = 0; T < NKT; ++T) {
        __bf16* bufc = smem + (T & 1) * 32768;
        __bf16* bufn = smem + ((T & 1) ^ 1) * 32768;
        const int kt1 = (T + 1) * 64, kt2 = (T + 2) * 64;

        // ---- phase 1: khalf 0, mhalf 0 ----
        {
            const __bf16* As = bufc;
            const __bf16* Bs = bufc + 16384;
            #pragma unroll
            for (int f = 0; f < 4; ++f)  af[f]  = *reinterpret_cast<const bf16x8*>(As + aoff + f * 512);
            #pragma unroll
            for (int nf = 0; nf < 4; ++nf) bfr[nf] = *reinterpret_cast<const bf16x8*>(Bs + boff + nf * 512);
            if (T + 1 < NKT) STAGE_SLAB(A, m0, kt1 + 32, bufn + 8192);
            __builtin_amdgcn_s_barrier();
            __builtin_amdgcn_s_setprio(1);
            #pragma unroll
            for (int f = 0; f < 4; ++f)
                #pragma unroll
                for (int nf = 0; nf < 4; ++nf)
                    acc[0][f][nf] = mfma16(af[f], bfr[nf], acc[0][f][nf]);
            __builtin_amdgcn_s_setprio(0);
            __builtin_amdgcn_s_barrier();
        }
        // ---- phase 2: khalf 0, mhalf 1 ----
        {
            const __bf16* As = bufc;
            #pragma unroll
            for (int f = 0; f < 4; ++f)  af[f] = *reinterpret_cast<const bf16x8*>(As + aoff + 2048 + f * 512);
            if (T + 1 < NKT) STAGE_SLAB(Bt, n0, kt1 + 32, bufn + 24576);
            __builtin_amdgcn_s_barrier();
            __builtin_amdgcn_s_setprio(1);
            #pragma unroll
            for (int f = 0; f < 4; ++f)
                #pragma unroll
                for (int nf = 0; nf < 4; ++nf)
                    acc[1][f][nf] = mfma16(af[f], bfr[nf], acc[1][f][nf]);
            __builtin_amdgcn_s_setprio(0);
            __builtin_amdgcn_s_barrier();
        }
        // ---- phase 3: khalf 1, mhalf 0 ----
        {
            const __bf16* As = bufc + 8192;
            const __bf16* Bs = bufc + 24576;
            #pragma unroll
            for (int f = 0; f < 4; ++f)  af[f]  = *reinterpret_cast<const bf16x8*>(As + aoff + f * 512);
            #pragma unroll
            for (int nf = 0; nf < 4; ++nf) bfr[nf] = *reinterpret_cast<const bf16x8*>(Bs + boff + nf * 512);
            if (T + 2 < NKT) STAGE_SLAB(A, m0, kt2, bufc);
            __builtin_amdgcn_s_barrier();
            __builtin_amdgcn_s_setprio(1);
            #pragma unroll
            for (int f = 0; f < 4; ++f)
                #pragma unroll
                for (int nf = 0; nf < 4; ++nf)
                    acc[0][f][nf] = mfma16(af[f], bfr[nf], acc[0][f][nf]);
            __builtin_amdgcn_s_setprio(0);
            __builtin_amdgcn_s_barrier();
        }
        // ---- phase 4: khalf 1, mhalf 1 + boundary vmcnt ----
        {
            const __bf16* As = bufc + 8192;
            #pragma unroll
            for (int f = 0; f < 4; ++f)  af[f] = *reinterpret_cast<const bf16x8*>(As + aoff + 2048 + f * 512);
            if (T + 2 < NKT) STAGE_SLAB(Bt, n0, kt2, bufc + 16384);
            __builtin_amdgcn_s_barrier();
            __builtin_amdgcn_s_setprio(1);
            #pragma unroll
            for (int f = 0; f < 4; ++f)
                #pragma unroll
                for (int nf = 0; nf < 4; ++nf)
                    acc[1][f][nf] = mfma16(af[f], bfr[nf], acc[1][f][nf]);
            __builtin_amdgcn_s_setprio(0);
            if (T < NKT - 2) asm volatile("s_waitcnt vmcnt(4)" ::: "memory");
            else             asm volatile("s_waitcnt vmcnt(0)" ::: "memory");
            __builtin_amdgcn_s_barrier();
        }
    }
#undef STAGE_SLAB

    #pragma unroll
    for (int mh = 0; mh < 2; ++mh)
        #pragma unroll
        for (int f = 0; f < 4; ++f)
            #pragma unroll
            for (int nf = 0; nf < 4; ++nf)
                #pragma unroll
                for (int r = 0; r < 4; ++r) {
                    const int row = m0 + wr * 128 + mh * 64 + f * 16 + l4 * 4 + r;
                    const int col = n0 + wc * 64 + nf * 16 + l15;
                    C[(size_t)row * N + col] = acc[mh][f][nf][r];
                }
}

// =====================================================================
// K8: 128x256-tile 2-phase GEMM for the Wo projection (unchanged).
// =====================================================================
__global__ __launch_bounds__(512, 2) void gemm8n_k(const __bf16* __restrict__ A,
                                                   const __bf16* __restrict__ Bt,
                                                   float* __restrict__ C,
                                                   int N, int K)
{
    __shared__ __align__(16) __bf16 smem[49152];   // 96 KB
    const int tid = threadIdx.x, wave = tid >> 6, lane = tid & 63;
    const int l15 = lane & 15, l4 = lane >> 4;
    const int wr = wave >> 2, wc = wave & 3;

    const int nwg = gridDim.x;
    const int swz = (blockIdx.x & 7) * (nwg >> 3) + (blockIdx.x >> 3);
    const int NBN = N >> 8;
    const int bm = swz / NBN, bn = swz - bm * NBN;
    const int m0 = bm << 7, n0 = bn << 8;

    const int NKT = K >> 6;

    const int srow   = tid >> 2;                       // 0..127
    const int schunk = (tid & 3) ^ ((tid >> 3) & 3);
    const int sdst   = wave * 512;                     // elems

    const int achunk = l4 ^ ((l15 >> 1) & 3);
    const int aoff = (wr * 64 + l15) * 32 + achunk * 8;   // + f*512 within A slab
    const int boff = (wc * 64 + l15) * 32 + achunk * 8;   // + nf*512 within B slab

    f32x4 acc[4][4] = {};
    bf16x8 af[4], bfr[4];

    // buffer b at b*24576 elems: A0 @0, A1 @4096, B0 @8192, B1 @16384
#define STAGE_A(koff, dstp) do {                                                  \
        gload16(A + (size_t)(m0 + srow) * K + (koff) + schunk * 8, (dstp) + sdst); \
    } while (0)
#define STAGE_B(koff, dstp) do {                                                  \
        const __bf16* _g = Bt + (size_t)(n0 + srow) * K + (koff) + schunk * 8;    \
        gload16(_g,                   (dstp) + sdst);                             \
        gload16(_g + (size_t)128 * K, (dstp) + sdst + 4096);                      \
    } while (0)

    STAGE_A(0,  smem);                 // T0.A0
    STAGE_B(0,  smem + 8192);          // T0.B0
    STAGE_A(32, smem + 4096);          // T0.A1
    STAGE_B(32, smem + 16384);         // T0.B1
    STAGE_A(64, smem + 24576);         // T1.A0
    STAGE_B(64, smem + 24576 + 8192);  // T1.B0
    asm volatile("s_waitcnt vmcnt(3)" ::: "memory");
    __builtin_amdgcn_s_barrier();

    #pragma unroll 1
    for (int T = 0; T < NKT; ++T) {
        __bf16* bufc = smem + (T & 1) * 24576;
        __bf16* bufn = smem + ((T & 1) ^ 1) * 24576;
        const int kt1 = (T + 1) * 64, kt2 = (T + 2) * 64;

        // ---- phase 1: khalf 0 ----
        {
            #pragma unroll
            for (int f = 0; f < 4; ++f)  af[f]  = *reinterpret_cast<const bf16x8*>(bufc + aoff + f * 512);
            #pragma unroll
            for (int nf = 0; nf < 4; ++nf) bfr[nf] = *reinterpret_cast<const bf16x8*>(bufc + 8192 + boff + nf * 512);
            if (T + 1 < NKT) { STAGE_A(kt1 + 32, bufn + 4096); STAGE_B(kt1 + 32, bufn + 16384); }
            __builtin_amdgcn_s_barrier();
            __builtin_amdgcn_s_setprio(1);
            #pragma unroll
            for (int f = 0; f < 4; ++f)
                #pragma unroll
                for (int nf = 0; nf < 4; ++nf)
                    acc[f][nf] = mfma16(af[f], bfr[nf], acc[f][nf]);
            __builtin_amdgcn_s_setprio(0);
            __builtin_amdgcn_s_barrier();
        }
        // ---- phase 2: khalf 1 + boundary vmcnt ----
        {
            #pragma unroll
            for (int f = 0; f < 4; ++f)  af[f]  = *reinterpret_cast<const bf16x8*>(bufc + 4096 + aoff + f * 512);
            #pragma unroll
            for (int nf = 0; nf < 4; ++nf) bfr[nf] = *reinterpret_cast<const bf16x8*>(bufc + 16384 + boff + nf * 512);
            if (T + 2 < NKT) { STAGE_A(kt2, bufc); STAGE_B(kt2, bufc + 8192); }
            __builtin_amdgcn_s_barrier();
            __builtin_amdgcn_s_setprio(1);
            #pragma unroll
            for (int f = 0; f < 4; ++f)
                #pragma unroll
                for (int nf = 0; nf < 4; ++nf)
                    acc[f][nf] = mfma16(af[f], bfr[nf], acc[f][nf]);
            __builtin_amdgcn_s_setprio(0);
            if (T < NKT - 2) asm volatile("s_waitcnt vmcnt(3)" ::: "memory");
            else             asm volatile("s_waitcnt vmcnt(0)" ::: "memory");
            __builtin_amdgcn_s_barrier();
        }
    }
#undef STAGE_A
#undef STAGE_B

    #pragma unroll
    for (int f = 0; f < 4; ++f)
        #pragma unroll
        for (int nf = 0; nf < 4; ++nf)
            #pragma unroll
            for (int r = 0; r < 4; ++r) {
                const int row = m0 + wr * 64 + f * 16 + l4 * 4 + r;
                const int col = n0 + wc * 64 + nf * 16 + l15;
                C[(size_t)row * N + col] = acc[f][nf][r];
            }
}

// =====================================================================
// K2: prep v3 — grid (SEQ/32, NKV, BATCH), 256 threads.
// =====================================================================
__global__ __launch_bounds__(256) void prep_k(const float* __restrict__ qkv,
                                              const float* __restrict__ norm_in,
                                              const int* __restrict__ pos_ids,
                                              __bf16* __restrict__ sq, __bf16* __restrict__ qr,
                                              __bf16* __restrict__ kr, __bf16* __restrict__ vt,
                                              float* __restrict__ nd, float* __restrict__ bnd,
                                              float* __restrict__ maxp)
{
    const int sc = blockIdx.x, kvh = blockIdx.y, b = blockIdx.z;
    const int s0 = sc * 32, t = threadIdx.x;
    const float scale = 0.08838834764831845f;      // 1/sqrt(128)
    const float s2 = scale * scale;
    const float NEG_LN_TH = -0.14391156831212787f; // -ln(10000)/64
    __shared__ float krn[32];

    // ---------- Q phase: 64 rows (2 heads x 32 s), 4 threads/row ----------
    {
        const int row = t >> 2;             // 0..63
        const int head = row >> 5, sl = row & 31;
        const int hq = kvh * 2 + head, nh = hq & 7;
        const int dq = (t & 3) * 16;        // pair-halves [dq,dq+16) & [dq+64,dq+80)
        const int pos = pos_ids[s0 + sl];
        const float* qp = qkv + (size_t)(b * SEQ + s0 + sl) * QKV_N + hq * 128;
        const float* np = norm_in + (b * NKV + nh) * 128;

        float x0[16], x1[16];
        #pragma unroll
        for (int i = 0; i < 16; i += 4) {
            *reinterpret_cast<float4*>(&x0[i]) = *reinterpret_cast<const float4*>(qp + dq + i);
            *reinterpret_cast<float4*>(&x1[i]) = *reinterpret_cast<const float4*>(qp + dq + 64 + i);
        }
        float nds = 0.f, qns = 0.f;
        bf16x8 sqv0[2], sqv1[2], qrv0[2], qrv1[2];
        #pragma unroll
        for (int i = 0; i < 16; ++i) {
            const int j = dq + i;           // 0..63
            float c, sn;
            __sincosf((float)pos * __expf((float)j * NEG_LN_TH), &sn, &c);
            qrv0[i >> 3][i & 7] = (__bf16)((x0[i] * c - x1[i] * sn) * scale);
            qrv1[i >> 3][i & 7] = (__bf16)((x1[i] * c + x0[i] * sn) * scale);
            const float sg0 = sigma_f(x0[i]), sg1 = sigma_f(x1[i]);
            sqv0[i >> 3][i & 7] = (__bf16)sg0;
            sqv1[i >> 3][i & 7] = (__bf16)sg1;
            nds += sg0 * np[j] + sg1 * np[j + 64];
            qns += (x0[i] * x0[i] + x1[i] * x1[i]) * s2;
        }
        __bf16* sqp = sq + ((size_t)(b * NH + hq) * SEQ + s0 + sl) * 128;
        __bf16* qrp = qr + ((size_t)(b * NH + hq) * SEQ + s0 + sl) * 128;
        *reinterpret_cast<bf16x8*>(sqp + dq)      = sqv0[0];
        *reinterpret_cast<bf16x8*>(sqp + dq + 8)  = sqv0[1];
        *reinterpret_cast<bf16x8*>(sqp + dq + 64) = sqv1[0];
        *reinterpret_cast<bf16x8*>(sqp + dq + 72) = sqv1[1];
        *reinterpret_cast<bf16x8*>(qrp + dq)      = qrv0[0];
        *reinterpret_cast<bf16x8*>(qrp + dq + 8)  = qrv0[1];
        *reinterpret_cast<bf16x8*>(qrp + dq + 64) = qrv1[0];
        *reinterpret_cast<bf16x8*>(qrp + dq + 72) = qrv1[1];

        nds += __shfl_xor(nds, 1); nds += __shfl_xor(nds, 2);
        qns += __shfl_xor(qns, 1); qns += __shfl_xor(qns, 2);
        if ((t & 3) == 0) {
            nd [(size_t)(b * NH + hq) * SEQ + s0 + sl] = nds;
            bnd[(size_t)(b * NH + hq) * SEQ + s0 + sl] = qns;
        }
    }

    // ---------- K phase: 32 rows, 4 threads/row (threads 0..127) ----------
    if (t < 128) {
        const int sl = t >> 2;
        const int dq = (t & 3) * 16;
        const int pos = pos_ids[s0 + sl];
        const float* kp = qkv + (size_t)(b * SEQ + s0 + sl) * QKV_N + 2048 + kvh * 128;
        float x0[16], x1[16];
        #pragma unroll
        for (int i = 0; i < 16; i += 4) {
            *reinterpret_cast<float4*>(&x0[i]) = *reinterpret_cast<const float4*>(kp + dq + i);
            *reinterpret_cast<float4*>(&x1[i]) = *reinterpret_cast<const float4*>(kp + dq + 64 + i);
        }
        bf16x8 kv0[2], kv1[2];
        float kns = 0.f;
        #pragma unroll
        for (int i = 0; i < 16; ++i) {
            const int j = dq + i;
            float c, sn;
            __sincosf((float)pos * __expf((float)j * NEG_LN_TH), &sn, &c);
            kv0[i >> 3][i & 7] = (__bf16)(x0[i] * c - x1[i] * sn);
            kv1[i >> 3][i & 7] = (__bf16)(x1[i] * c + x0[i] * sn);
            kns += x0[i] * x0[i] + x1[i] * x1[i];
        }
        __bf16* krp = kr + ((size_t)(b * NKV + kvh) * SEQ + s0 + sl) * 128;
        *reinterpret_cast<bf16x8*>(krp + dq)      = kv0[0];
        *reinterpret_cast<bf16x8*>(krp + dq + 8)  = kv0[1];
        *reinterpret_cast<bf16x8*>(krp + dq + 64) = kv1[0];
        *reinterpret_cast<bf16x8*>(krp + dq + 72) = kv1[1];
        kns += __shfl_xor(kns, 1); kns += __shfl_xor(kns, 2);
        if ((t & 3) == 0) krn[sl] = kns;
    }

    // ---------- V phase: transpose via LDS, coalesced vt writes ----------
    __shared__ float vl[128][33];
    {
        const int sl = t >> 3, dch = (t & 7) * 16;
        const float* vp = qkv + (size_t)(b * SEQ + s0 + sl) * QKV_N + 3072 + kvh * 128 + dch;
        float xv[16];
        #pragma unroll
        for (int i = 0; i < 16; i += 4)
            *reinterpret_cast<float4*>(&xv[i]) = *reinterpret_cast<const float4*>(vp + i);
        #pragma unroll
        for (int i = 0; i < 16; ++i) vl[dch + i][sl] = xv[i];
    }
    __syncthreads();
    if (t == 0) {
        float mx = 0.f;
        #pragma unroll
        for (int i = 0; i < 32; ++i) mx = fmaxf(mx, krn[i]);
        maxp[((b * NKV + kvh) << 6) + sc] = mx;
    }
    {
        const int d = t >> 1, sh = (t & 1) * 16;
        bf16x8 o0, o1;
        #pragma unroll
        for (int j = 0; j < 8; ++j) o0[j] = (__bf16)vl[d][sh + j];
        #pragma unroll
        for (int j = 0; j < 8; ++j) o1[j] = (__bf16)vl[d][sh + 8 + j];
        __bf16* vp = vt + ((size_t)((b * NKV + kvh) * 128 + d)) * SEQ + s0 + sh;
        *reinterpret_cast<bf16x8*>(vp)     = o0;
        *reinterpret_cast<bf16x8*>(vp + 8) = o1;
    }
}

// =====================================================================
// K3: memory_output = (sigma_q @ mem) / nd, write g*val into combined
// =====================================================================
__global__ __launch_bounds__(256) void memout_k(const __bf16* __restrict__ sq,
                                                const float* __restrict__ mem_in,
                                                const float* __restrict__ nd,
                                                const float* __restrict__ gate,
                                                __bf16* __restrict__ cb)
{
    __shared__ __align__(16) __bf16 mt[128][136];   // mem^T [e][d]
    const int tid = threadIdx.x;
    const int h = blockIdx.y, b = blockIdx.z;
    const int s0 = blockIdx.x * 64;

    const float* mem = mem_in + (size_t)(b * NKV + (h & 7)) * 16384;
    for (int i = tid; i < 16384; i += 256) {
        int dd = i >> 7, e = i & 127;
        mt[e][dd] = (__bf16)mem[i];
    }
    __syncthreads();

    const int wave = tid >> 6, lane = tid & 63, l15 = lane & 15, l4 = lane >> 4;
    f32x4 acc[8] = {};
    const __bf16* sqb = sq + ((size_t)(b * NH + h) * SEQ + s0 + wave * 16 + l15) * 128;
    #pragma unroll
    for (int kb = 0; kb < 4; ++kb) {
        bf16x8 a = *reinterpret_cast<const bf16x8*>(sqb + kb * 32 + l4 * 8);
        #pragma unroll
        for (int nc = 0; nc < 8; ++nc) {
            bf16x8 bb = *reinterpret_cast<bf16x8*>(&mt[nc * 16 + l15][kb * 32 + l4 * 8]);
            acc[nc] = mfma16(a, bb, acc[nc]);
        }
    }
    float g = 1.f / (1.f + __expf(-gate[h]));
    #pragma unroll
    for (int r = 0; r < 4; ++r) {
        int srow = s0 + wave * 16 + l4 * 4 + r;
        float scl = g / nd[(size_t)(b * NH + h) * SEQ + srow];
        __bf16* cbp = cb + (size_t)(b * SEQ + srow) * HID + h * 128;
        #pragma unroll
        for (int nc = 0; nc < 8; ++nc)
            cbp[nc * 16 + l15] = (__bf16)(acc[nc][r] * scl);
    }
}

// =====================================================================
// K5: updated_memory partials + sigma_k column-sum partials. v2:
// e-dimension split across 2 blocks -> grid (NSPLIT, 16, BATCH) = 256
// blocks (full GPU vs 128 = half before). y = eh*8 + h. Per-thread work
// halves (acc[8][4]); sv LDS halves; float4 part stores. Costs one extra
// read of the k-slab (staged by both eh blocks).
// =====================================================================
__global__ __launch_bounds__(256) void memupd_k(const float* __restrict__ qkv,
                                                float* __restrict__ part,
                                                float* __restrict__ npart)
{
    const int sp = blockIdx.x, yy = blockIdx.y, b = blockIdx.z;
    const int h = yy & 7, eh = yy >> 3;
    const int tid = threadIdx.x;
    const int tx = tid & 15, ty = tid >> 4;   // d-block tx*8 (8 d), e-block eh*64+ty*4 (4 e)
    __shared__ __align__(16) float sk[8][128];
    __shared__ __align__(16) float sv[8][64];
    float acc[8][4] = {};
    float nacc = 0.f;                          // eh==0, threads 0..127

    const int s0 = sp * (SEQ / NSPLIT);
    for (int so = 0; so < SEQ / NSPLIT; so += 8) {
        for (int i = tid; i < 8 * 128; i += 256) {
            int rr = i >> 7, dd = i & 127;
            sk[rr][dd] = sigma_f(qkv[(size_t)(b * SEQ + s0 + so + rr) * QKV_N + 2048 + h * 128 + dd]);
        }
        {
            const int rr = tid >> 6, ee = tid & 63;     // rows 0..3 and 4..7
            const size_t base = (size_t)(b * SEQ + s0 + so) * QKV_N + 3072 + h * 128 + eh * 64 + ee;
            sv[rr][ee]     = qkv[base + (size_t)rr * QKV_N];
            sv[rr + 4][ee] = qkv[base + (size_t)(rr + 4) * QKV_N];
        }
        __syncthreads();
        if (eh == 0 && tid < 128) {
            #pragma unroll
            for (int rr = 0; rr < 8; ++rr) nacc += sk[rr][tid];
        }
        #pragma unroll
        for (int rr = 0; rr < 8; ++rr) {
            float4 k0 = *reinterpret_cast<float4*>(&sk[rr][tx * 8]);
            float4 k1 = *reinterpret_cast<float4*>(&sk[rr][tx * 8 + 4]);
            float4 v0 = *reinterpret_cast<float4*>(&sv[rr][ty * 4]);
            float kreg[8] = {k0.x,k0.y,k0.z,k0.w,k1.x,k1.y,k1.z,k1.w};
            float vreg[4] = {v0.x,v0.y,v0.z,v0.w};
            #pragma unroll
            for (int i = 0; i < 8; ++i)
                #pragma unroll
                for (int j2 = 0; j2 < 4; ++j2)
                    acc[i][j2] += kreg[i] * vreg[j2];
        }
        __syncthreads();
    }
    float* pb = part + ((size_t)sp * (BATCH * NKV) + b * NKV + h) * 16384;
    #pragma unroll
    for (int i = 0; i < 8; ++i) {
        float4 o; o.x = acc[i][0]; o.y = acc[i][1]; o.z = acc[i][2]; o.w = acc[i][3];
        *reinterpret_cast<float4*>(&pb[(tx * 8 + i) * 128 + eh * 64 + ty * 4]) = o;
    }
    if (eh == 0 && tid < 128)
        npart[((size_t)sp * (BATCH * NKV) + b * NKV + h) * 128 + tid] = nacc;
}

// =====================================================================
// K6: fused reduce — [0,1024) mem partials + mem_in ; [1024,1040) norm.
// =====================================================================
__global__ __launch_bounds__(256) void memrednorm_k(const float* __restrict__ part,
                                                    const float* __restrict__ mem_in,
                                                    float* __restrict__ out_mem,
                                                    const float* __restrict__ npart,
                                                    const float* __restrict__ norm_in,
                                                    float* __restrict__ out_norm)
{
    const int bid = blockIdx.x;
    if (bid < 1024) {
        const size_t i = (size_t)bid * 256 + threadIdx.x;   // 262144 total
        float a = mem_in[i];
        #pragma unroll
        for (int sp = 0; sp < NSPLIT; ++sp) a += part[(size_t)sp * 262144 + i];
        out_mem[i] = a;
    } else if (threadIdx.x < 128) {
        const int bh = bid - 1024, d = threadIdx.x;
        float a = norm_in[bh * 128 + d];
        #pragma unroll
        for (int sp = 0; sp < NSPLIT; ++sp)
            a += npart[((size_t)sp * (BATCH * NKV) + bh) * 128 + d];
        out_norm[bh * 128 + d] = a;
    }
}

// =====================================================================
// K7: flash causal attention v5 — EXACT round-2 code (best measured:
// 82.5 +/- 0.2 us across 5 dispatches). v6's swizzled-plds variant
// regressed to 100 us; reverted.
// =====================================================================
__global__ __launch_bounds__(256, 2) void attn_k(const __bf16* __restrict__ qr,
                                                 const __bf16* __restrict__ kr,
                                                 const __bf16* __restrict__ vt,
                                                 const float* __restrict__ gate,
                                                 const float* __restrict__ bnd,
                                                 const float* __restrict__ maxp,
                                                 __bf16* __restrict__ cb)
{
    __shared__ __align__(16) char smem[81920];
    char* ksB = smem;                        // K swz [128][128] bf16 (32 KB)
    char* vsB = smem + 32768;                // V^T swz [128][128]    (32 KB)
    char* pB  = smem + 65536;                // plds 4 x [32][64] lin (16 KB)
    float*  red  = (float*)smem;             // epilogue overlay
    float*  lred = (float*)(smem + 65536);   // epilogue overlay

    const int tid = threadIdx.x, wave = tid >> 6, lane = tid & 63;
    const int l15 = lane & 15, l4 = lane >> 4;
    const int e3 = l15 & 7, e2 = e3 >> 2;
    const int ksub = wave >> 1;                        // k-subtile parity
    const int wq   = wave & 1;                         // q 32-row half

    // ---- XCD swizzle: each XCD owns 2 full (b,kvh) groups ----
    const int n   = blockIdx.x + 16 * (blockIdx.y + 16 * blockIdx.z);
    const int xcd = n & 7, i64 = n >> 3;
    const int grp = xcd * 2 + (i64 >> 5);
    const int within = i64 & 31;
    const int b   = grp >> 3;
    const int kvh = grp & 7;
    const int h   = kvh * 2 + (within >> 4);
    const int x   = within & 15;

    const __bf16* kbase = kr + (size_t)(b * NKV + kvh) * SEQ * 128;
    const __bf16* vbase = vt + (size_t)(b * NKV + kvh) * 128 * SEQ;
    const float* bbase  = bnd + (size_t)(b * NH + h) * SEQ;

    const float g  = 1.f / (1.f + __expf(-gate[h]));
    const float gi = 1.f - g;
    float kn2 = 0.f;
    const float* mp = maxp + (b * NKV + kvh) * 64;
    #pragma unroll
    for (int i = 0; i < 64; i += 4) {
        const float4 v = *reinterpret_cast<const float4*>(mp + i);
        kn2 = fmaxf(kn2, fmaxf(fmaxf(v.x, v.y), fmaxf(v.z, v.w)));
    }
    const float knmax = sqrtf(kn2);

    bf16x8 ones;
    #pragma unroll
    for (int j = 0; j < 8; ++j) ones[j] = (__bf16)1.0f;

    // ---- precomputed staging addresses (bytes) ----
    const int srow = wave * 32 + l4;                   // + j*4 per issue
    const int chA  = (lane & 15) ^ l4;
    const char* KG0 = (const char*)kbase + srow * 256 + chA * 16;          // j even
    const char* KG1 = (const char*)kbase + srow * 256 + ((chA ^ 4) * 16);  // j odd
    const char* VG0 = (const char*)vbase + srow * 4096 + chA * 16;
    const char* VG1 = (const char*)vbase + srow * 4096 + ((chA ^ 4) * 16);
    __bf16* kdst = (__bf16*)(ksB + wave * 8192);
    __bf16* vdst = (__bf16*)(vsB + wave * 8192);

    // ---- precomputed read bases (byte offsets; XOR split into fields) ----
    const int t16 = (l4 ^ (e3 & 3)) * 16;
    const int KBe = l15 * 256 + ksub * 16384 + t16 + e2 * 64;
    const int KBo = l15 * 256 + ksub * 16384 + t16 + (1 ^ e2) * 64;
    const int VB0 = l15 * 256 + t16 + e2 * 64 + ksub * 128;
    const int VB1 = l15 * 256 + t16 + (1 ^ e2) * 64 + ksub * 128;
    // plds (linear): write base + {r*128 + sub*32 + m*2048}; read base + {m*2048 + half*64}
    const int PWw = wave * 4096 + l4 * 512 + l15 * 2;
    const int PWr = wave * 4096 + l15 * 128 + l4 * 16;

#define ISSUE_K(ktrow) do {                                                      \
        const int _ko = (ktrow) * 256;                                           \
        _Pragma("unroll")                                                        \
        for (int _j = 0; _j < 8; ++_j)                                           \
            gload16((const __bf16*)(((_j & 1) ? KG1 : KG0) + _ko + _j * 1024),   \
                    kdst + _j * 512);                                            \
    } while (0)
#define ISSUE_V(ktrow) do {                                                      \
        const int _vo = (ktrow) * 2;                                             \
        _Pragma("unroll")                                                        \
        for (int _j = 0; _j < 8; ++_j)                                           \
            gload16((const __bf16*)(((_j & 1) ? VG1 : VG0) + _vo + _j * 16384),  \
                    vdst + _j * 512);                                            \
    } while (0)

    #pragma unroll 1
    for (int tile = 0; tile < 2; ++tile) {
        const int q0 = (tile == 0 ? x : 31 - x) * 64;
        const int qw = q0 + wq * 32;
        const int NT = (q0 >> 6) + 1;                  // # 64-kt subtiles
        const int NI = (NT + 1) >> 1;                  // 128-kt iterations

        bf16x8 af[2][4];
        float m_r[2][4];
        #pragma unroll
        for (int m = 0; m < 2; ++m) {
            const __bf16* qb = qr + ((size_t)(b * NH + h) * SEQ + qw + m * 16 + l15) * 128;
            #pragma unroll
            for (int kb = 0; kb < 4; ++kb)
                af[m][kb] = *reinterpret_cast<const bf16x8*>(qb + kb * 32 + l4 * 8);
            #pragma unroll
            for (int r = 0; r < 4; ++r)
                m_r[m][r] = sqrtf(bbase[qw + m * 16 + l4 * 4 + r]) * knmax + 1.0f;
        }

        f32x4 o0[8] = {}, o1[8] = {};
        f32x4 lc0 = {}, lc1 = {};

        // ---- prologue: stage iter-0 K and V ----
        ISSUE_K(0);
        ISSUE_V(0);
        asm volatile("s_waitcnt vmcnt(8)" ::: "memory");   // K(0) landed
        __builtin_amdgcn_sched_barrier(0);
        __builtin_amdgcn_s_barrier();

        #pragma unroll 1
        for (int it = 0; it < NI; ++it) {
            const int s = 2 * it + ksub;
            const bool act  = (s < NT);
            const bool more = (it + 1 < NI);

            f32x4 s0[4] = {}, s1[4] = {};
            if (act) {
                // ---- QK^T (Ks reads: 2 bases + immediates) ----
                __builtin_amdgcn_s_setprio(1);
                #pragma unroll
                for (int kb = 0; kb < 4; ++kb) {
                    const int kbb = ((kb & 1) ? KBo : KBe) + (kb >> 1) * 128;
                    #pragma unroll
                    for (int sub = 0; sub < 4; ++sub) {
                        bf16x8 bb = *reinterpret_cast<const bf16x8*>(ksB + kbb + sub * 4096);
                        s0[sub] = mfma16(af[0][kb], bb, s0[sub]);
                        s1[sub] = mfma16(af[1][kb], bb, s1[sub]);
                    }
                }
                __builtin_amdgcn_s_setprio(0);
            }
            __builtin_amdgcn_sched_barrier(0);
            __builtin_amdgcn_s_barrier();              // (1) all done reading Ks(it)

            if (more) ISSUE_K((it + 1) * 128);

            if (act) {
                // ---- exp + causal mask + plds store (wave-local) ----
                #pragma unroll
                for (int r = 0; r < 4; ++r) {
                    const int q0r = qw + l4 * 4 + r;
                    const int q1r = q0r + 16;
                    #pragma unroll
                    for (int sub = 0; sub < 4; ++sub) {
                        const int key = s * 64 + sub * 16 + l15;
                        float p0 = __expf(s0[sub][r] - m_r[0][r]);
                        float p1 = __expf(s1[sub][r] - m_r[1][r]);
                        p0 = (key <= q0r) ? p0 : 0.f;
                        p1 = (key <= q1r) ? p1 : 0.f;
                        *(__bf16*)(pB + PWw + r * 128 + sub * 32)        = (__bf16)p0;
                        *(__bf16*)(pB + PWw + 2048 + r * 128 + sub * 32) = (__bf16)p1;
                    }
                }
            }
            if (more) asm volatile("s_waitcnt vmcnt(8)" ::: "memory");  // V(it) landed
            else      asm volatile("s_waitcnt vmcnt(0)" ::: "memory");
            __builtin_amdgcn_sched_barrier(0);
            __builtin_amdgcn_s_barrier();              // (2) Vs(it) visible

            if (act) {
                // ---- P reads (1 base + immediates) + PV ----
                bf16x8 a00 = *reinterpret_cast<const bf16x8*>(pB + PWr);
                bf16x8 a01 = *reinterpret_cast<const bf16x8*>(pB + PWr + 64);
                bf16x8 a10 = *reinterpret_cast<const bf16x8*>(pB + PWr + 2048);
                bf16x8 a11 = *reinterpret_cast<const bf16x8*>(pB + PWr + 2048 + 64);
                __builtin_amdgcn_s_setprio(1);
                lc0 = mfma16(a00, ones, lc0); lc0 = mfma16(a01, ones, lc0);
                lc1 = mfma16(a10, ones, lc1); lc1 = mfma16(a11, ones, lc1);
                #pragma unroll
                for (int nc = 0; nc < 8; ++nc) {
                    bf16x8 b0 = *reinterpret_cast<const bf16x8*>(vsB + VB0 + nc * 4096);
                    bf16x8 b1 = *reinterpret_cast<const bf16x8*>(vsB + VB1 + nc * 4096);
                    o0[nc] = mfma16(a00, b0, o0[nc]); o0[nc] = mfma16(a01, b1, o0[nc]);
                    o1[nc] = mfma16(a10, b0, o1[nc]); o1[nc] = mfma16(a11, b1, o1[nc]);
                }
                __builtin_amdgcn_s_setprio(0);
            }
            __builtin_amdgcn_sched_barrier(0);
            __builtin_amdgcn_s_barrier();              // (3) all done reading Vs(it)

            if (more) {
                ISSUE_V((it + 1) * 128);
                asm volatile("s_waitcnt vmcnt(8)" ::: "memory");        // K(it+1) landed
            } else {
                asm volatile("s_waitcnt vmcnt(0)" ::: "memory");
            }
            __builtin_amdgcn_sched_barrier(0);
            __builtin_amdgcn_s_barrier();              // (4) Ks(it+1) visible
        }

        // ---- cross-pair reduction: wave w+2 -> wave w (same q-rows) ----
        if (wave >= 2) {
            float* rb = red + (wave - 2) * 4224;       // 32 rows x stride 132
            #pragma unroll
            for (int nc = 0; nc < 8; ++nc)
                #pragma unroll
                for (int r = 0; r < 4; ++r) {
                    rb[(l4 * 4 + r) * 132 + nc * 16 + l15]        = o0[nc][r];
                    rb[(16 + l4 * 4 + r) * 132 + nc * 16 + l15]   = o1[nc][r];
                }
            if (l15 == 0) {
                float* lb = lred + (wave - 2) * 32;
                #pragma unroll
                for (int r = 0; r < 4; ++r) {
                    lb[l4 * 4 + r]      = lc0[r];
                    lb[16 + l4 * 4 + r] = lc1[r];
                }
            }
        }
        __syncthreads();
        if (wave < 2) {
            float* rb = red + wave * 4224;
            const float* lb = lred + wave * 32;
            #pragma unroll
            for (int r = 0; r < 4; ++r) {
                const int qrow = qw + l4 * 4 + r;
                const float i0 = gi / (lc0[r] + lb[l4 * 4 + r]);
                const float i1 = gi / (lc1[r] + lb[16 + l4 * 4 + r]);
                __bf16* c0 = cb + (size_t)(b * SEQ + qrow) * HID + h * 128;
                __bf16* c1 = cb + (size_t)(b * SEQ + qrow + 16) * HID + h * 128;
                #pragma unroll
                for (int nc = 0; nc < 8; ++nc) {
                    const int dd = nc * 16 + l15;
                    const float v0 = o0[nc][r] + rb[(l4 * 4 + r) * 132 + dd];
                    const float v1 = o1[nc][r] + rb[(16 + l4 * 4 + r) * 132 + dd];
                    c0[dd] = (__bf16)((float)c0[dd] + v0 * i0);
                    c1[dd] = (__bf16)((float)c1[dd] + v1 * i1);
                }
            }
        }
        __syncthreads();   // red/lred overlay dead before next tile restages Ks
    }
#undef ISSUE_K
#undef ISSUE_V
}

// =====================================================================
extern "C" void kernel_launch(void* const* d_in, const int* in_sizes, int n_in,
                              void* d_out, int out_size, void* d_ws, size_t ws_size,
                              hipStream_t stream)
{
    const float* hidden  = (const float*)d_in[0];
    const float* Wq      = (const float*)d_in[1];
    const float* Wk      = (const float*)d_in[2];
    const float* Wv      = (const float*)d_in[3];
    const float* Wo      = (const float*)d_in[4];
    const float* gate    = (const float*)d_in[5];
    const float* mem_in  = (const float*)d_in[6];
    const float* norm_in = (const float*)d_in[7];
    const int*   pos     = (const int*)d_in[8];

    float* out_final = (float*)d_out;                  // (B,S,HID)
    float* out_mem   = out_final + (size_t)BATCH * SEQ * HID;     // (B,8,128,128)
    float* out_norm  = out_mem + (size_t)BATCH * NKV * 128 * 128; // (B,8,1,128)

    char* ws = (char*)d_ws;
    float*  qkv  = (float*)(ws + OFF_QKV);
    __bf16* sq   = (__bf16*)(ws + OFF_SQ);
    __bf16* qrb  = (__bf16*)(ws + OFF_QR);
    __bf16* krb  = (__bf16*)(ws + OFF_KR);
    __bf16* vtb  = (__bf16*)(ws + OFF_VT);
    float*  nd   = (float*)(ws + OFF_ND);
    __bf16* cb   = (__bf16*)(ws + OFF_CB);
    float*  part = (float*)(ws + OFF_PART);
    float*  bnd  = (float*)(ws + OFF_BND);
    float*  maxp = (float*)(ws + OFF_MAXP);
    float*  npart = (float*)(ws + OFF_NPART);
    // overlays (lifetimes disjoint from the named owners):
    __bf16* hb   = (__bf16*)(ws + OFF_SQ);    // bf16 hidden  [4096][2048], dead after gemm1
    __bf16* qkvT = (__bf16*)(ws + OFF_QR);    // bf16 W_qkv^T [4096][2048], dead after gemm1
    __bf16* woT  = (__bf16*)(ws + OFF_PART);  // bf16 Wo^T    [2048][2048], after memrednorm

    // 0. fused pre-pass: hidden f2b + Wq/Wk/Wv transposes (1 launch)
    pre_k<<<6144, 256, 0, stream>>>(hidden, Wq, Wk, Wv, hb, qkvT);

    // 1. fused QKV projection: [4096 x 2048] @ [2048 x 4096], 256 blocks (1/CU)
    gemm8_k<<<(M_ROWS / 256) * (QKV_N / 256), 512, 0, stream>>>(hb, qkvT, qkv, QKV_N, HID);

    // 2. prep (overwrites hb/qkvT — now dead); k-norm maxima fused in
    prep_k<<<dim3(SEQ / 32, NKV, BATCH), 256, 0, stream>>>(qkv, norm_in, pos, sq, qrb, krb, vtb,
                                                           nd, bnd, maxp);

    // 3. memory_output -> combined (g * memout / nd)
    memout_k<<<dim3(SEQ / 64, NH, BATCH), 256, 0, stream>>>(sq, mem_in, nd, gate, cb);

    // 4/5. updated_memory v2 (e-split, 256 blocks) and fused reduce
    memupd_k<<<dim3(NSPLIT, 16, BATCH), 256, 0, stream>>>(qkv, part, npart);
    memrednorm_k<<<1040, 256, 0, stream>>>(part, mem_in, out_mem, npart, norm_in, out_norm);

    // 6b. Wo^T (overlays part — dead after memrednorm)
    tr_k<<<dim3(HID / 64, HID / 64), 256, 0, stream>>>(Wo, woT, HID, HID);

    // 7. causal attention v5 (reverted to best-measured round-2 code)
    attn_k<<<dim3(16, NH, BATCH), 256, 0, stream>>>(qrb, krb, vtb, gate, bnd, maxp, cb);

    // 8. output projection: [4096 x 2048] @ [2048 x 2048], 128x256 tiles -> 256 blocks
    gemm8n_k<<<(M_ROWS / 128) * (HID / 256), 512, 0, stream>>>(cb, woT, out_final, HID, HID);
}